// Round 2
// baseline (1608.251 us; speedup 1.0000x reference)
//
#include <hip/hip_runtime.h>
#include <hip/hip_bf16.h>
#include <hip/hip_fp16.h>

// Problem constants
#define NPTS   65536
#define BATCH  8
#define CH     64
#define RES    32
#define RCELLS 32768          // 32^3
#define NEG_SLOPE 0.1f
#define BN_EPS 1e-4f

typedef float    f32x4 __attribute__((ext_vector_type(4)));
typedef _Float16 f16x8 __attribute__((ext_vector_type(8)));
typedef _Float16 f16x4 __attribute__((ext_vector_type(4)));
typedef _Float16 f16x2 __attribute__((ext_vector_type(2)));

// Workspace layout (float offsets)
#define OFF_SUMS   0                                 // 24 floats
#define OFF_SCALE  24                                // 8 uints
#define OFF_CNT    32                                // B*32768 ints (zeroed)
#define OFF_IDX    (OFF_CNT + BATCH*RCELLS)          // B*N ints
#define OFF_CSTART (OFF_IDX + BATCH*NPTS)            // B*32768 ints (unused now)
#define OFF_ORDER  (OFF_CSTART + BATCH*RCELLS)       // B*N ints (unused now)
#define OFF_BN     (OFF_ORDER + BATCH*NPTS)          // 4*64 floats
#define OFF_WP1    (OFF_BN + 256)                    // 110592 f16 = 55296 fl
#define OFF_WP2    (OFF_WP1 + 55296)
#define OFF_FT     (OFF_WP2 + 55296)                 // (unused now)
#define OFF_GA     (OFF_FT + 16777216)               // 16777216 f16 = 8388608 fl
#define OFF_GB     (OFF_GA + 8388608)

__device__ inline float waveReduceSum(float v) {
#pragma unroll
    for (int off = 32; off > 0; off >>= 1) v += __shfl_down(v, off, 64);
    return v;
}
__device__ inline float waveReduceMax(float v) {
#pragma unroll
    for (int off = 32; off > 0; off >>= 1) v = fmaxf(v, __shfl_down(v, off, 64));
    return v;
}

// ---------------- per-batch coordinate sums ----------------
__global__ __launch_bounds__(256) void k_stats_sum(const float* __restrict__ coords,
                                                   float* __restrict__ sums) {
    __shared__ float sm[3][4];
    int b = blockIdx.x >> 3, chunk = blockIdx.x & 7;
    const float* cb = coords + (size_t)b * 3 * NPTS;
    float s0 = 0.f, s1 = 0.f, s2 = 0.f;
    for (int i = threadIdx.x; i < 8192; i += 256) {
        int n = chunk * 8192 + i;
        s0 += cb[n];
        s1 += cb[n + NPTS];
        s2 += cb[n + 2 * NPTS];
    }
    s0 = waveReduceSum(s0); s1 = waveReduceSum(s1); s2 = waveReduceSum(s2);
    int lane = threadIdx.x & 63, wid = threadIdx.x >> 6;
    if (lane == 0) { sm[0][wid] = s0; sm[1][wid] = s1; sm[2][wid] = s2; }
    __syncthreads();
    if (threadIdx.x == 0) {
        atomicAdd(&sums[b * 3 + 0], sm[0][0] + sm[0][1] + sm[0][2] + sm[0][3]);
        atomicAdd(&sums[b * 3 + 1], sm[1][0] + sm[1][1] + sm[1][2] + sm[1][3]);
        atomicAdd(&sums[b * 3 + 2], sm[2][0] + sm[2][1] + sm[2][2] + sm[2][3]);
    }
}

// ---------------- per-batch max ||coord - mean|| ----------------
__global__ __launch_bounds__(256) void k_stats_max(const float* __restrict__ coords,
                                                   const float* __restrict__ sums,
                                                   unsigned int* __restrict__ scaleBits) {
    __shared__ float sm[4];
    int b = blockIdx.x >> 3, chunk = blockIdx.x & 7;
    const float* cb = coords + (size_t)b * 3 * NPTS;
    float mx = sums[b * 3 + 0] * (1.f / NPTS);
    float my = sums[b * 3 + 1] * (1.f / NPTS);
    float mz = sums[b * 3 + 2] * (1.f / NPTS);
    float m = 0.f;
    for (int i = threadIdx.x; i < 8192; i += 256) {
        int n = chunk * 8192 + i;
        float dx = cb[n] - mx, dy = cb[n + NPTS] - my, dz = cb[n + 2 * NPTS] - mz;
        m = fmaxf(m, sqrtf(dx * dx + dy * dy + dz * dz));
    }
    m = waveReduceMax(m);
    int lane = threadIdx.x & 63, wid = threadIdx.x >> 6;
    if (lane == 0) sm[wid] = m;
    __syncthreads();
    if (threadIdx.x == 0) {
        float r = fmaxf(fmaxf(sm[0], sm[1]), fmaxf(sm[2], sm[3]));
        atomicMax(&scaleBits[b], __float_as_uint(r));
    }
}

// ---------------- voxel index + int counts ----------------
__global__ __launch_bounds__(256) void k_vox_assign(const float* __restrict__ coords,
                                                    const float* __restrict__ sums,
                                                    const unsigned int* __restrict__ scaleBits,
                                                    int* __restrict__ idxb,
                                                    int* __restrict__ cnt) {
    int g = blockIdx.x * 256 + threadIdx.x;       // 0 .. B*N-1
    int b = g >> 16, n = g & (NPTS - 1);
    const float* cb = coords + (size_t)b * 3 * NPTS;
    float scale2 = __uint_as_float(scaleBits[b]) * 2.f;
    int v[3];
#pragma unroll
    for (int d = 0; d < 3; ++d) {
        float mean = sums[b * 3 + d] * (1.f / NPTS);
        float x = (cb[d * NPTS + n] - mean) / scale2 + 0.5f;
        x *= (float)RES;
        x = fminf(fmaxf(x, 0.f), (float)(RES - 1));
        v[d] = (int)rintf(x);
    }
    int id = (v[0] * RES + v[1]) * RES + v[2];
    idxb[b * NPTS + n] = id;
    atomicAdd(&cnt[b * RCELLS + id], 1);
}

// ---------------- fused transpose + pre-scaled scatter-average ----------------
// One thread per point. Coalesced channel-major loads of features (lane index ==
// point index), feature row held in registers, scaled by 1/max(cnt,1), then
// 32 packed-f16 atomic adds (global_atomic_pk_add_f16 via unsafeAtomicAdd)
// into the channels-last grid gA [b][ct][cell][32].
__global__ __launch_bounds__(256) void k_scatter(const float* __restrict__ features,
                                                 const int* __restrict__ idxb,
                                                 const int* __restrict__ cnt,
                                                 _Float16* __restrict__ gA) {
    int g0 = blockIdx.x * 256;                    // block-aligned global point id
    int b = g0 >> 16;
    int nb = g0 & (NPTS - 1);
    int tid = threadIdx.x;
    const float* fb = features + (size_t)b * CH * NPTS + nb + tid;

    // load + convert this point's 64 channels into registers (coalesced per c)
    f16x2 row[32];
#pragma unroll
    for (int k = 0; k < 32; ++k) {
        float v0 = fb[(size_t)(2 * k) * NPTS];
        float v1 = fb[(size_t)(2 * k + 1) * NPTS];
        f16x2 r; r[0] = (_Float16)v0; r[1] = (_Float16)v1;
        row[k] = r;
    }

    int n = nb + tid;
    int cell = idxb[b * NPTS + n];
    int c = cnt[b * RCELLS + cell];
    float invf = 1.f / (float)max(c, 1);
    _Float16 invh = (_Float16)invf;
    f16x2 inv2; inv2[0] = invh; inv2[1] = invh;

#pragma unroll
    for (int ct = 0; ct < 2; ++ct) {
        __half2* base = (__half2*)(gA + ((size_t)(b * 2 + ct) * RCELLS + cell) * 32);
#pragma unroll
        for (int k = 0; k < 16; ++k) {
            f16x2 s = row[ct * 16 + k] * inv2;
            __half2 hv = *(__half2*)&s;
            unsafeAtomicAdd(base + k, hv);         // global_atomic_pk_add_f16
        }
    }
}

// ---------------- weight repack (f16, MFMA A-layout) + BN constants ----------
__global__ __launch_bounds__(256) void k_prep(const float* __restrict__ w,
                                              const float* __restrict__ bias,
                                              const float* __restrict__ g,
                                              const float* __restrict__ be,
                                              const float* __restrict__ m,
                                              const float* __restrict__ v,
                                              _Float16* __restrict__ wP,
                                              float* __restrict__ bnA,
                                              float* __restrict__ bnB) {
    int s = blockIdx.x * 256 + threadIdx.x;       // 0 .. 110591
    int ci_in = s & 31;
    int t  = s >> 5;
    int co = t & 63;
    int tc = t >> 6;                               // tap*2 + ct
    int ct = tc & 1;
    int tap = tc >> 1;
    int ci = ct * 32 + ci_in;
    wP[s] = (_Float16)w[co * 1728 + ci * 27 + tap];
    if (s < 64) {
        float A = g[s] / sqrtf(v[s] + BN_EPS);
        bnA[s] = A;
        bnB[s] = (bias[s] - m[s]) * A + be[s];
    }
}

// ---------------- 3x3x3 conv via f16 MFMA (implicit shift-GEMM) -------------
__global__ __launch_bounds__(256, 2) void k_conv(const _Float16* __restrict__ gIn,
                                                 _Float16* __restrict__ gOut,
                                                 const _Float16* __restrict__ wP,
                                                 const float* __restrict__ bnA,
                                                 const float* __restrict__ bnB) {
    __shared__ _Float16 sIn[3 * 10 * 34 * 32];     // 65280 B, halo-padded
    int bi = blockIdx.x;
    int b  = bi >> 7;
    int rem = bi & 127;
    int z  = rem >> 2;
    int yg = rem & 3;
    int tid = threadIdx.x;
    int wid = tid >> 6;
    int lane = tid & 63;
    int l15 = lane & 15, quad = lane >> 4;

    f32x4 acc[4][4];
#pragma unroll
    for (int mt = 0; mt < 4; ++mt)
#pragma unroll
        for (int nt = 0; nt < 4; ++nt) acc[mt][nt] = (f32x4){0.f, 0.f, 0.f, 0.f};

    const f16x8* wp8 = (const f16x8*)wP;

    int bbase[4];
#pragma unroll
    for (int nt = 0; nt < 4; ++nt) {
        int yl = 2 * wid + (nt >> 1);
        int x  = ((nt & 1) << 4) + l15;
        bbase[nt] = ((10 + (yl + 1)) * 34 + (x + 1)) * 32 + quad * 8; // zz=1
    }

    for (int ct = 0; ct < 2; ++ct) {
        const _Float16* gin = gIn + (size_t)(b * 2 + ct) * (RCELLS * 32);
#pragma unroll
        for (int it = 0; it < 16; ++it) {
            int s = tid + it * 256;                 // 16B chunk id
            if (s < 4080) {
                int cc  = s & 3;
                int pos = s >> 2;                   // 0..1019
                int xx  = pos % 34;
                int t2  = pos / 34;
                int yy  = t2 % 10;
                int zz  = t2 / 10;
                int x = xx - 1, y = yg * 8 + yy - 1, z0 = z + zz - 1;
                f32x4 val = {0.f, 0.f, 0.f, 0.f};
                if ((unsigned)x < 32u && (unsigned)y < 32u && (unsigned)z0 < 32u)
                    val = *(const f32x4*)(gin + ((size_t)((z0 * 32 + y) * 32 + x)) * 32 + cc * 8);
                *(f32x4*)(sIn + (size_t)s * 8) = val;
            }
        }
        __syncthreads();

#pragma unroll
        for (int dz = -1; dz <= 1; ++dz)
#pragma unroll
        for (int dy = -1; dy <= 1; ++dy)
#pragma unroll
        for (int dx = -1; dx <= 1; ++dx) {
            int tap = (dz + 1) * 9 + (dy + 1) * 3 + (dx + 1);
            f16x8 aF[4];
#pragma unroll
            for (int mt = 0; mt < 4; ++mt)
                aF[mt] = wp8[tap * 512 + ct * 256 + mt * 64 + l15 * 4 + quad];
            f16x8 bF[4];
            int off = ((dz + 1) * 340 + dy * 34 + dx) * 32 - 340 * 32;
#pragma unroll
            for (int nt = 0; nt < 4; ++nt)
                bF[nt] = *(const f16x8*)(sIn + bbase[nt] + off);
#pragma unroll
            for (int mt = 0; mt < 4; ++mt)
#pragma unroll
                for (int nt = 0; nt < 4; ++nt)
                    acc[mt][nt] = __builtin_amdgcn_mfma_f32_16x16x32_f16(
                        aF[mt], bF[nt], acc[mt][nt], 0, 0, 0);
        }
        __syncthreads();
    }

#pragma unroll
    for (int nt = 0; nt < 4; ++nt) {
        int y = yg * 8 + 2 * wid + (nt >> 1);
        int x = ((nt & 1) << 4) + l15;
        int cell = z * 1024 + y * 32 + x;
#pragma unroll
        for (int mt = 0; mt < 4; ++mt) {
            int cob = mt * 16 + quad * 4;           // 4 consecutive co
            f32x4 An = *(const f32x4*)(bnA + cob);
            f32x4 Bn = *(const f32x4*)(bnB + cob);
            f16x4 hv;
#pragma unroll
            for (int r = 0; r < 4; ++r) {
                float t = acc[mt][nt][r] * An[r] + Bn[r];
                t = (t >= 0.f) ? t : NEG_SLOPE * t;
                hv[r] = (_Float16)t;
            }
            _Float16* op = gOut + ((size_t)(b * 2 + (cob >> 5)) * RCELLS + cell) * 32 + (cob & 31);
            *(f16x4*)op = hv;
        }
    }
}

// ---------------- trilinear devoxelize (recomputes norm coords) -------------
__global__ __launch_bounds__(256) void k_devox(const _Float16* __restrict__ gA,
                                               const float* __restrict__ coords,
                                               const float* __restrict__ sums,
                                               const unsigned int* __restrict__ scaleBits,
                                               float* __restrict__ out) {
    int g = blockIdx.x * 256 + threadIdx.x;        // 0 .. B*N-1
    int b = g >> 16, n = g & (NPTS - 1);
    const float* cb = coords + (size_t)b * 3 * NPTS;
    float scale2 = __uint_as_float(scaleBits[b]) * 2.f;
    float nc[3];
#pragma unroll
    for (int d = 0; d < 3; ++d) {
        float mean = sums[b * 3 + d] * (1.f / NPTS);
        float x = (cb[d * NPTS + n] - mean) / scale2 + 0.5f;
        x *= (float)RES;
        nc[d] = fminf(fmaxf(x, 0.f), (float)(RES - 1));
    }
    float tx = nc[0], ty = nc[1], tz = nc[2];
    float lx = floorf(tx), ly = floorf(ty), lz = floorf(tz);
    float fx = tx - lx, fy = ty - ly, fz = tz - lz;
    int x0 = (int)lx, y0 = (int)ly, z0 = (int)lz;
    int x1 = min(x0 + 1, RES - 1), y1 = min(y0 + 1, RES - 1), z1 = min(z0 + 1, RES - 1);
    int ids[8];
    float wc[8];
    ids[0] = (x0 * RES + y0) * RES + z0;
    ids[1] = (x0 * RES + y0) * RES + z1;
    ids[2] = (x0 * RES + y1) * RES + z0;
    ids[3] = (x0 * RES + y1) * RES + z1;
    ids[4] = (x1 * RES + y0) * RES + z0;
    ids[5] = (x1 * RES + y0) * RES + z1;
    ids[6] = (x1 * RES + y1) * RES + z0;
    ids[7] = (x1 * RES + y1) * RES + z1;
    float gx = 1.f - fx, gy = 1.f - fy, gz = 1.f - fz;
    wc[0] = gx * gy * gz; wc[1] = gx * gy * fz;
    wc[2] = gx * fy * gz; wc[3] = gx * fy * fz;
    wc[4] = fx * gy * gz; wc[5] = fx * gy * fz;
    wc[6] = fx * fy * gz; wc[7] = fx * fy * fz;

#pragma unroll
    for (int ct = 0; ct < 2; ++ct) {
        float acc[32];
#pragma unroll
        for (int j = 0; j < 32; ++j) acc[j] = 0.f;
        const _Float16* gb = gA + (size_t)(b * 2 + ct) * RCELLS * 32;
#pragma unroll
        for (int c8 = 0; c8 < 8; ++c8) {
            const _Float16* p = gb + (size_t)ids[c8] * 32;
            float wgt = wc[c8];
#pragma unroll
            for (int k = 0; k < 4; ++k) {
                f16x8 v = *(const f16x8*)(p + k * 8);
#pragma unroll
                for (int j = 0; j < 8; ++j)
                    acc[k * 8 + j] += wgt * (float)v[j];
            }
        }
        float* ob = out + (size_t)b * CH * NPTS + (size_t)(ct * 32) * NPTS + n;
#pragma unroll
        for (int j = 0; j < 32; ++j)
            ob[(size_t)j * NPTS] = acc[j];
    }
}

extern "C" void kernel_launch(void* const* d_in, const int* in_sizes, int n_in,
                              void* d_out, int out_size, void* d_ws, size_t ws_size,
                              hipStream_t stream) {
    const float* features = (const float*)d_in[0];
    const float* coords   = (const float*)d_in[1];
    const float* w1  = (const float*)d_in[2];
    const float* b1  = (const float*)d_in[3];
    const float* g1  = (const float*)d_in[4];
    const float* be1 = (const float*)d_in[5];
    const float* m1  = (const float*)d_in[6];
    const float* v1  = (const float*)d_in[7];
    const float* w2  = (const float*)d_in[8];
    const float* b2  = (const float*)d_in[9];
    const float* g2  = (const float*)d_in[10];
    const float* be2 = (const float*)d_in[11];
    const float* m2  = (const float*)d_in[12];
    const float* v2  = (const float*)d_in[13];

    float* ws = (float*)d_ws;
    float*        sums      = ws + OFF_SUMS;
    unsigned int* scaleBits = (unsigned int*)(ws + OFF_SCALE);
    int*          cnt       = (int*)(ws + OFF_CNT);
    int*          idxb      = (int*)(ws + OFF_IDX);
    float*        bnA1      = ws + OFF_BN;
    float*        bnB1      = ws + OFF_BN + 64;
    float*        bnA2      = ws + OFF_BN + 128;
    float*        bnB2      = ws + OFF_BN + 192;
    _Float16*     wP1       = (_Float16*)(ws + OFF_WP1);
    _Float16*     wP2       = (_Float16*)(ws + OFF_WP2);
    _Float16*     gA        = (_Float16*)(ws + OFF_GA);
    _Float16*     gB        = (_Float16*)(ws + OFF_GB);

    // zero: sums + scaleBits + cnt
    (void)hipMemsetAsync(ws, 0, (size_t)(OFF_IDX) * sizeof(float), stream);
    // zero: gA accumulation grid (B*2*RCELLS*32 f16 = 33.5 MB)
    (void)hipMemsetAsync(gA, 0, (size_t)BATCH * 2 * RCELLS * 32 * sizeof(_Float16),
                         stream);

    k_stats_sum<<<64, 256, 0, stream>>>(coords, sums);
    k_stats_max<<<64, 256, 0, stream>>>(coords, sums, scaleBits);
    k_vox_assign<<<(BATCH * NPTS) / 256, 256, 0, stream>>>(coords, sums, scaleBits,
                                                           idxb, cnt);
    k_scatter<<<(BATCH * NPTS) / 256, 256, 0, stream>>>(features, idxb, cnt, gA);
    k_prep<<<432, 256, 0, stream>>>(w1, b1, g1, be1, m1, v1, wP1, bnA1, bnB1);
    k_prep<<<432, 256, 0, stream>>>(w2, b2, g2, be2, m2, v2, wP2, bnA2, bnB2);
    k_conv<<<BATCH * RES * 4, 256, 0, stream>>>(gA, gB, wP1, bnA1, bnB1);
    k_conv<<<BATCH * RES * 4, 256, 0, stream>>>(gB, gA, wP2, bnA2, bnB2);
    k_devox<<<(BATCH * NPTS) / 256, 256, 0, stream>>>(gA, coords, sums, scaleBits,
                                                      (float*)d_out);

    // append passthrough coords
    (void)hipMemcpyAsync((float*)d_out + (size_t)BATCH * CH * NPTS, coords,
                         (size_t)BATCH * 3 * NPTS * sizeof(float),
                         hipMemcpyDeviceToDevice, stream);
}

// Round 3
// 752.184 us; speedup vs baseline: 2.1381x; 2.1381x over previous
//
#include <hip/hip_runtime.h>
#include <hip/hip_bf16.h>
#include <hip/hip_fp16.h>

// Problem constants
#define NPTS   65536
#define BATCH  8
#define CH     64
#define RES    32
#define RCELLS 32768          // 32^3
#define NEG_SLOPE 0.1f
#define BN_EPS 1e-4f

typedef float    f32x4 __attribute__((ext_vector_type(4)));
typedef _Float16 f16x8 __attribute__((ext_vector_type(8)));
typedef _Float16 f16x4 __attribute__((ext_vector_type(4)));

// Workspace layout (float offsets)
#define OFF_SUMS   0                                 // 24 floats
#define OFF_SCALE  24                                // 8 uints
#define OFF_CNT    32                                // B*32768 ints (zeroed)
#define OFF_IDX    (OFF_CNT + BATCH*RCELLS)          // B*N ints
#define OFF_CSTART (OFF_IDX + BATCH*NPTS)            // B*32768 ints
#define OFF_ORDER  (OFF_CSTART + BATCH*RCELLS)       // B*N ints
#define OFF_BN     (OFF_ORDER + BATCH*NPTS)          // 4*64 floats
#define OFF_WP1    (OFF_BN + 256)                    // 110592 f16 = 55296 fl
#define OFF_WP2    (OFF_WP1 + 55296)
#define OFF_FT     (OFF_WP2 + 55296)                 // B*N*64 f16 = 16777216 fl
#define OFF_GA     (OFF_FT + 16777216)               // 16777216 f16 = 8388608 fl
#define OFF_GB     (OFF_GA + 8388608)

__device__ inline float waveReduceSum(float v) {
#pragma unroll
    for (int off = 32; off > 0; off >>= 1) v += __shfl_down(v, off, 64);
    return v;
}
__device__ inline float waveReduceMax(float v) {
#pragma unroll
    for (int off = 32; off > 0; off >>= 1) v = fmaxf(v, __shfl_down(v, off, 64));
    return v;
}

// ---------------- per-batch coordinate sums ----------------
__global__ __launch_bounds__(256) void k_stats_sum(const float* __restrict__ coords,
                                                   float* __restrict__ sums) {
    __shared__ float sm[3][4];
    int b = blockIdx.x >> 3, chunk = blockIdx.x & 7;
    const float* cb = coords + (size_t)b * 3 * NPTS;
    float s0 = 0.f, s1 = 0.f, s2 = 0.f;
    for (int i = threadIdx.x; i < 8192; i += 256) {
        int n = chunk * 8192 + i;
        s0 += cb[n];
        s1 += cb[n + NPTS];
        s2 += cb[n + 2 * NPTS];
    }
    s0 = waveReduceSum(s0); s1 = waveReduceSum(s1); s2 = waveReduceSum(s2);
    int lane = threadIdx.x & 63, wid = threadIdx.x >> 6;
    if (lane == 0) { sm[0][wid] = s0; sm[1][wid] = s1; sm[2][wid] = s2; }
    __syncthreads();
    if (threadIdx.x == 0) {
        atomicAdd(&sums[b * 3 + 0], sm[0][0] + sm[0][1] + sm[0][2] + sm[0][3]);
        atomicAdd(&sums[b * 3 + 1], sm[1][0] + sm[1][1] + sm[1][2] + sm[1][3]);
        atomicAdd(&sums[b * 3 + 2], sm[2][0] + sm[2][1] + sm[2][2] + sm[2][3]);
    }
}

// ---------------- per-batch max ||coord - mean|| ----------------
__global__ __launch_bounds__(256) void k_stats_max(const float* __restrict__ coords,
                                                   const float* __restrict__ sums,
                                                   unsigned int* __restrict__ scaleBits) {
    __shared__ float sm[4];
    int b = blockIdx.x >> 3, chunk = blockIdx.x & 7;
    const float* cb = coords + (size_t)b * 3 * NPTS;
    float mx = sums[b * 3 + 0] * (1.f / NPTS);
    float my = sums[b * 3 + 1] * (1.f / NPTS);
    float mz = sums[b * 3 + 2] * (1.f / NPTS);
    float m = 0.f;
    for (int i = threadIdx.x; i < 8192; i += 256) {
        int n = chunk * 8192 + i;
        float dx = cb[n] - mx, dy = cb[n + NPTS] - my, dz = cb[n + 2 * NPTS] - mz;
        m = fmaxf(m, sqrtf(dx * dx + dy * dy + dz * dz));
    }
    m = waveReduceMax(m);
    int lane = threadIdx.x & 63, wid = threadIdx.x >> 6;
    if (lane == 0) sm[wid] = m;
    __syncthreads();
    if (threadIdx.x == 0) {
        float r = fmaxf(fmaxf(sm[0], sm[1]), fmaxf(sm[2], sm[3]));
        atomicMax(&scaleBits[b], __float_as_uint(r));
    }
}

// ---------------- voxel index + int counts ----------------
__global__ __launch_bounds__(256) void k_vox_assign(const float* __restrict__ coords,
                                                    const float* __restrict__ sums,
                                                    const unsigned int* __restrict__ scaleBits,
                                                    int* __restrict__ idxb,
                                                    int* __restrict__ cnt) {
    int g = blockIdx.x * 256 + threadIdx.x;       // 0 .. B*N-1
    int b = g >> 16, n = g & (NPTS - 1);
    const float* cb = coords + (size_t)b * 3 * NPTS;
    float scale2 = __uint_as_float(scaleBits[b]) * 2.f;
    int v[3];
#pragma unroll
    for (int d = 0; d < 3; ++d) {
        float mean = sums[b * 3 + d] * (1.f / NPTS);
        float x = (cb[d * NPTS + n] - mean) / scale2 + 0.5f;
        x *= (float)RES;
        x = fminf(fmaxf(x, 0.f), (float)(RES - 1));
        v[d] = (int)rintf(x);
    }
    int id = (v[0] * RES + v[1]) * RES + v[2];
    idxb[b * NPTS + n] = id;
    atomicAdd(&cnt[b * RCELLS + id], 1);
}

// ---------------- per-batch exclusive prefix scan of cell counts ------------
__global__ __launch_bounds__(256) void k_scan(const int* __restrict__ cnt,
                                              int* __restrict__ cellStart) {
    __shared__ int bufA[256], bufB[256];
    int b = blockIdx.x, tid = threadIdx.x;
    const int* cb = cnt + b * RCELLS;
    int sum = 0;
    for (int i = 0; i < 128; ++i) sum += cb[tid * 128 + i];
    bufA[tid] = sum;
    __syncthreads();
    int* src = bufA; int* dst = bufB;
    for (int off = 1; off < 256; off <<= 1) {
        int v = src[tid];
        if (tid >= off) v += src[tid - off];
        dst[tid] = v;
        __syncthreads();
        int* t = src; src = dst; dst = t;
    }
    int run = (tid > 0) ? src[tid - 1] : 0;        // exclusive
    int* cs = cellStart + b * RCELLS;
    for (int i = 0; i < 128; ++i) {
        int c = cb[tid * 128 + i];
        cs[tid * 128 + i] = run;
        run += c;
    }
}

// ---------------- rank points into cell-sorted order ----------------
// Mutates cellStart: afterwards cellStart[c] == end offset of cell c.
__global__ __launch_bounds__(256) void k_rank(const int* __restrict__ idxb,
                                              int* __restrict__ cellStart,
                                              int* __restrict__ order) {
    int g = blockIdx.x * 256 + threadIdx.x;
    int b = g >> 16, n = g & (NPTS - 1);
    int cell = idxb[b * NPTS + n];
    int pos = atomicAdd(&cellStart[b * RCELLS + cell], 1);
    order[b * NPTS + pos] = n;
}

// ---------------- features fp32 [b][c][n] -> f16 [b][n][64] ----------------
__global__ __launch_bounds__(256) void k_transpose(const float* __restrict__ f,
                                                   _Float16* __restrict__ featT) {
    int g = blockIdx.x * 256 + threadIdx.x;        // 0 .. B*N-1
    int b = g >> 16, n = g & (NPTS - 1);
    const float* fb = f + (size_t)b * CH * NPTS + n;
    _Float16* dst = featT + (size_t)g * 64;
#pragma unroll
    for (int k = 0; k < 8; ++k) {
        f16x8 hv;
#pragma unroll
        for (int j = 0; j < 8; ++j)
            hv[j] = (_Float16)fb[(size_t)(k * 8 + j) * NPTS];
        *(f16x8*)(dst + k * 8) = hv;
    }
}

// ---------------- gather-average into f16 channels-last grid ----------------
// gA layout: [b][ct(2)][cell][32] f16. One thread per (b, cell, ct).
// 8-point unrolled: batch the order[] loads, then issue all 32 row loads
// concurrently -> ~2 memory latencies per 8 points instead of ~2 per point.
__global__ __launch_bounds__(256) void k_gather(const _Float16* __restrict__ featT,
                                                const int* __restrict__ order,
                                                const int* __restrict__ cellStart,
                                                const int* __restrict__ cnt,
                                                _Float16* __restrict__ gA) {
    int t = blockIdx.x * 256 + threadIdx.x;        // 0 .. B*RCELLS*2-1
    int b = t >> 16;
    int r = t & 65535;
    int cell = r >> 1;
    int ct = r & 1;
    int e = cellStart[b * RCELLS + cell];          // post-rank: end offset
    int c = cnt[b * RCELLS + cell];
    int s = e - c;
    float acc[32];
#pragma unroll
    for (int j = 0; j < 32; ++j) acc[j] = 0.f;
    const int* ob = order + b * NPTS;
    const _Float16* fb = featT + (((size_t)b << 16)) * 64 + ct * 32;

    int p = s;
    for (; p + 8 <= e; p += 8) {
        int n[8];
#pragma unroll
        for (int u = 0; u < 8; ++u) n[u] = ob[p + u];   // 8 independent loads
        f16x8 v[8][4];
#pragma unroll
        for (int u = 0; u < 8; ++u) {
            const _Float16* q = fb + (size_t)n[u] * 64;
#pragma unroll
            for (int k = 0; k < 4; ++k)
                v[u][k] = *(const f16x8*)(q + k * 8);   // 32 loads in flight
        }
#pragma unroll
        for (int u = 0; u < 8; ++u)
#pragma unroll
            for (int k = 0; k < 4; ++k)
#pragma unroll
                for (int j = 0; j < 8; ++j)
                    acc[k * 8 + j] += (float)v[u][k][j];
    }
    for (; p < e; ++p) {
        int n = ob[p];
        const _Float16* q = fb + (size_t)n * 64;
#pragma unroll
        for (int k = 0; k < 4; ++k) {
            f16x8 vv = *(const f16x8*)(q + k * 8);
#pragma unroll
            for (int j = 0; j < 8; ++j)
                acc[k * 8 + j] += (float)vv[j];
        }
    }

    float inv = 1.f / (float)max(c, 1);
    _Float16* dst = gA + ((size_t)(b * 2 + ct) * RCELLS + cell) * 32;
#pragma unroll
    for (int k = 0; k < 4; ++k) {
        f16x8 hv;
#pragma unroll
        for (int j = 0; j < 8; ++j)
            hv[j] = (_Float16)(acc[k * 8 + j] * inv);
        *(f16x8*)(dst + k * 8) = hv;
    }
}

// ---------------- weight repack (f16, MFMA A-layout) + BN constants ----------
__global__ __launch_bounds__(256) void k_prep(const float* __restrict__ w,
                                              const float* __restrict__ bias,
                                              const float* __restrict__ g,
                                              const float* __restrict__ be,
                                              const float* __restrict__ m,
                                              const float* __restrict__ v,
                                              _Float16* __restrict__ wP,
                                              float* __restrict__ bnA,
                                              float* __restrict__ bnB) {
    int s = blockIdx.x * 256 + threadIdx.x;       // 0 .. 110591
    int ci_in = s & 31;
    int t  = s >> 5;
    int co = t & 63;
    int tc = t >> 6;                               // tap*2 + ct
    int ct = tc & 1;
    int tap = tc >> 1;
    int ci = ct * 32 + ci_in;
    wP[s] = (_Float16)w[co * 1728 + ci * 27 + tap];
    if (s < 64) {
        float A = g[s] / sqrtf(v[s] + BN_EPS);
        bnA[s] = A;
        bnB[s] = (bias[s] - m[s]) * A + be[s];
    }
}

// ---------------- 3x3x3 conv via f16 MFMA (implicit shift-GEMM) -------------
__global__ __launch_bounds__(256, 2) void k_conv(const _Float16* __restrict__ gIn,
                                                 _Float16* __restrict__ gOut,
                                                 const _Float16* __restrict__ wP,
                                                 const float* __restrict__ bnA,
                                                 const float* __restrict__ bnB) {
    __shared__ _Float16 sIn[3 * 10 * 34 * 32];     // 65280 B, halo-padded
    int bi = blockIdx.x;
    int b  = bi >> 7;
    int rem = bi & 127;
    int z  = rem >> 2;
    int yg = rem & 3;
    int tid = threadIdx.x;
    int wid = tid >> 6;
    int lane = tid & 63;
    int l15 = lane & 15, quad = lane >> 4;

    f32x4 acc[4][4];
#pragma unroll
    for (int mt = 0; mt < 4; ++mt)
#pragma unroll
        for (int nt = 0; nt < 4; ++nt) acc[mt][nt] = (f32x4){0.f, 0.f, 0.f, 0.f};

    const f16x8* wp8 = (const f16x8*)wP;

    int bbase[4];
#pragma unroll
    for (int nt = 0; nt < 4; ++nt) {
        int yl = 2 * wid + (nt >> 1);
        int x  = ((nt & 1) << 4) + l15;
        bbase[nt] = ((10 + (yl + 1)) * 34 + (x + 1)) * 32 + quad * 8; // zz=1
    }

    for (int ct = 0; ct < 2; ++ct) {
        const _Float16* gin = gIn + (size_t)(b * 2 + ct) * (RCELLS * 32);
#pragma unroll
        for (int it = 0; it < 16; ++it) {
            int s = tid + it * 256;                 // 16B chunk id
            if (s < 4080) {
                int cc  = s & 3;
                int pos = s >> 2;                   // 0..1019
                int xx  = pos % 34;
                int t2  = pos / 34;
                int yy  = t2 % 10;
                int zz  = t2 / 10;
                int x = xx - 1, y = yg * 8 + yy - 1, z0 = z + zz - 1;
                f32x4 val = {0.f, 0.f, 0.f, 0.f};
                if ((unsigned)x < 32u && (unsigned)y < 32u && (unsigned)z0 < 32u)
                    val = *(const f32x4*)(gin + ((size_t)((z0 * 32 + y) * 32 + x)) * 32 + cc * 8);
                *(f32x4*)(sIn + (size_t)s * 8) = val;
            }
        }
        __syncthreads();

#pragma unroll
        for (int dz = -1; dz <= 1; ++dz)
#pragma unroll
        for (int dy = -1; dy <= 1; ++dy)
#pragma unroll
        for (int dx = -1; dx <= 1; ++dx) {
            int tap = (dz + 1) * 9 + (dy + 1) * 3 + (dx + 1);
            f16x8 aF[4];
#pragma unroll
            for (int mt = 0; mt < 4; ++mt)
                aF[mt] = wp8[tap * 512 + ct * 256 + mt * 64 + l15 * 4 + quad];
            f16x8 bF[4];
            int off = ((dz + 1) * 340 + dy * 34 + dx) * 32 - 340 * 32;
#pragma unroll
            for (int nt = 0; nt < 4; ++nt)
                bF[nt] = *(const f16x8*)(sIn + bbase[nt] + off);
#pragma unroll
            for (int mt = 0; mt < 4; ++mt)
#pragma unroll
                for (int nt = 0; nt < 4; ++nt)
                    acc[mt][nt] = __builtin_amdgcn_mfma_f32_16x16x32_f16(
                        aF[mt], bF[nt], acc[mt][nt], 0, 0, 0);
        }
        __syncthreads();
    }

#pragma unroll
    for (int nt = 0; nt < 4; ++nt) {
        int y = yg * 8 + 2 * wid + (nt >> 1);
        int x = ((nt & 1) << 4) + l15;
        int cell = z * 1024 + y * 32 + x;
#pragma unroll
        for (int mt = 0; mt < 4; ++mt) {
            int cob = mt * 16 + quad * 4;           // 4 consecutive co
            f32x4 An = *(const f32x4*)(bnA + cob);
            f32x4 Bn = *(const f32x4*)(bnB + cob);
            f16x4 hv;
#pragma unroll
            for (int r = 0; r < 4; ++r) {
                float t = acc[mt][nt][r] * An[r] + Bn[r];
                t = (t >= 0.f) ? t : NEG_SLOPE * t;
                hv[r] = (_Float16)t;
            }
            _Float16* op = gOut + ((size_t)(b * 2 + (cob >> 5)) * RCELLS + cell) * 32 + (cob & 31);
            *(f16x4*)op = hv;
        }
    }
}

// ---------------- trilinear devoxelize (recomputes norm coords) -------------
__global__ __launch_bounds__(256) void k_devox(const _Float16* __restrict__ gA,
                                               const float* __restrict__ coords,
                                               const float* __restrict__ sums,
                                               const unsigned int* __restrict__ scaleBits,
                                               float* __restrict__ out) {
    int g = blockIdx.x * 256 + threadIdx.x;        // 0 .. B*N-1
    int b = g >> 16, n = g & (NPTS - 1);
    const float* cb = coords + (size_t)b * 3 * NPTS;
    float scale2 = __uint_as_float(scaleBits[b]) * 2.f;
    float nc[3];
#pragma unroll
    for (int d = 0; d < 3; ++d) {
        float mean = sums[b * 3 + d] * (1.f / NPTS);
        float x = (cb[d * NPTS + n] - mean) / scale2 + 0.5f;
        x *= (float)RES;
        nc[d] = fminf(fmaxf(x, 0.f), (float)(RES - 1));
    }
    float tx = nc[0], ty = nc[1], tz = nc[2];
    float lx = floorf(tx), ly = floorf(ty), lz = floorf(tz);
    float fx = tx - lx, fy = ty - ly, fz = tz - lz;
    int x0 = (int)lx, y0 = (int)ly, z0 = (int)lz;
    int x1 = min(x0 + 1, RES - 1), y1 = min(y0 + 1, RES - 1), z1 = min(z0 + 1, RES - 1);
    int ids[8];
    float wc[8];
    ids[0] = (x0 * RES + y0) * RES + z0;
    ids[1] = (x0 * RES + y0) * RES + z1;
    ids[2] = (x0 * RES + y1) * RES + z0;
    ids[3] = (x0 * RES + y1) * RES + z1;
    ids[4] = (x1 * RES + y0) * RES + z0;
    ids[5] = (x1 * RES + y0) * RES + z1;
    ids[6] = (x1 * RES + y1) * RES + z0;
    ids[7] = (x1 * RES + y1) * RES + z1;
    float gx = 1.f - fx, gy = 1.f - fy, gz = 1.f - fz;
    wc[0] = gx * gy * gz; wc[1] = gx * gy * fz;
    wc[2] = gx * fy * gz; wc[3] = gx * fy * fz;
    wc[4] = fx * gy * gz; wc[5] = fx * gy * fz;
    wc[6] = fx * fy * gz; wc[7] = fx * fy * fz;

#pragma unroll
    for (int ct = 0; ct < 2; ++ct) {
        float acc[32];
#pragma unroll
        for (int j = 0; j < 32; ++j) acc[j] = 0.f;
        const _Float16* gb = gA + (size_t)(b * 2 + ct) * RCELLS * 32;
#pragma unroll
        for (int c8 = 0; c8 < 8; ++c8) {
            const _Float16* p = gb + (size_t)ids[c8] * 32;
            float wgt = wc[c8];
#pragma unroll
            for (int k = 0; k < 4; ++k) {
                f16x8 v = *(const f16x8*)(p + k * 8);
#pragma unroll
                for (int j = 0; j < 8; ++j)
                    acc[k * 8 + j] += wgt * (float)v[j];
            }
        }
        float* ob = out + (size_t)b * CH * NPTS + (size_t)(ct * 32) * NPTS + n;
#pragma unroll
        for (int j = 0; j < 32; ++j)
            ob[(size_t)j * NPTS] = acc[j];
    }
}

extern "C" void kernel_launch(void* const* d_in, const int* in_sizes, int n_in,
                              void* d_out, int out_size, void* d_ws, size_t ws_size,
                              hipStream_t stream) {
    const float* features = (const float*)d_in[0];
    const float* coords   = (const float*)d_in[1];
    const float* w1  = (const float*)d_in[2];
    const float* b1  = (const float*)d_in[3];
    const float* g1  = (const float*)d_in[4];
    const float* be1 = (const float*)d_in[5];
    const float* m1  = (const float*)d_in[6];
    const float* v1  = (const float*)d_in[7];
    const float* w2  = (const float*)d_in[8];
    const float* b2  = (const float*)d_in[9];
    const float* g2  = (const float*)d_in[10];
    const float* be2 = (const float*)d_in[11];
    const float* m2  = (const float*)d_in[12];
    const float* v2  = (const float*)d_in[13];

    float* ws = (float*)d_ws;
    float*        sums      = ws + OFF_SUMS;
    unsigned int* scaleBits = (unsigned int*)(ws + OFF_SCALE);
    int*          cnt       = (int*)(ws + OFF_CNT);
    int*          idxb      = (int*)(ws + OFF_IDX);
    int*          cellStart = (int*)(ws + OFF_CSTART);
    int*          order     = (int*)(ws + OFF_ORDER);
    float*        bnA1      = ws + OFF_BN;
    float*        bnB1      = ws + OFF_BN + 64;
    float*        bnA2      = ws + OFF_BN + 128;
    float*        bnB2      = ws + OFF_BN + 192;
    _Float16*     wP1       = (_Float16*)(ws + OFF_WP1);
    _Float16*     wP2       = (_Float16*)(ws + OFF_WP2);
    _Float16*     featT     = (_Float16*)(ws + OFF_FT);
    _Float16*     gA        = (_Float16*)(ws + OFF_GA);
    _Float16*     gB        = (_Float16*)(ws + OFF_GB);

    // zero: sums + scaleBits + cnt
    (void)hipMemsetAsync(ws, 0, (size_t)(OFF_IDX) * sizeof(float), stream);

    k_stats_sum<<<64, 256, 0, stream>>>(coords, sums);
    k_stats_max<<<64, 256, 0, stream>>>(coords, sums, scaleBits);
    k_vox_assign<<<(BATCH * NPTS) / 256, 256, 0, stream>>>(coords, sums, scaleBits,
                                                           idxb, cnt);
    k_scan<<<BATCH, 256, 0, stream>>>(cnt, cellStart);
    k_rank<<<(BATCH * NPTS) / 256, 256, 0, stream>>>(idxb, cellStart, order);
    k_transpose<<<(BATCH * NPTS) / 256, 256, 0, stream>>>(features, featT);
    k_gather<<<(BATCH * RCELLS * 2) / 256, 256, 0, stream>>>(featT, order, cellStart,
                                                             cnt, gA);
    k_prep<<<432, 256, 0, stream>>>(w1, b1, g1, be1, m1, v1, wP1, bnA1, bnB1);
    k_prep<<<432, 256, 0, stream>>>(w2, b2, g2, be2, m2, v2, wP2, bnA2, bnB2);
    k_conv<<<BATCH * RES * 4, 256, 0, stream>>>(gA, gB, wP1, bnA1, bnB1);
    k_conv<<<BATCH * RES * 4, 256, 0, stream>>>(gB, gA, wP2, bnA2, bnB2);
    k_devox<<<(BATCH * NPTS) / 256, 256, 0, stream>>>(gA, coords, sums, scaleBits,
                                                      (float*)d_out);

    // append passthrough coords
    (void)hipMemcpyAsync((float*)d_out + (size_t)BATCH * CH * NPTS, coords,
                         (size_t)BATCH * 3 * NPTS * sizeof(float),
                         hipMemcpyDeviceToDevice, stream);
}

// Round 4
// 722.614 us; speedup vs baseline: 2.2256x; 1.0409x over previous
//
#include <hip/hip_runtime.h>
#include <hip/hip_bf16.h>
#include <hip/hip_fp16.h>

// Problem constants
#define NPTS   65536
#define BATCH  8
#define CH     64
#define RES    32
#define RCELLS 32768          // 32^3
#define NEG_SLOPE 0.1f
#define BN_EPS 1e-4f
#define GSPLIT 4              // point-parallel lanes per (cell, ct)

typedef float    f32x4 __attribute__((ext_vector_type(4)));
typedef _Float16 f16x8 __attribute__((ext_vector_type(8)));
typedef _Float16 f16x4 __attribute__((ext_vector_type(4)));

// Workspace layout (float offsets)
#define OFF_SUMS   0                                 // 24 floats
#define OFF_SCALE  24                                // 8 uints
#define OFF_CNT    32                                // B*32768 ints (zeroed)
#define OFF_IDX    (OFF_CNT + BATCH*RCELLS)          // B*N ints
#define OFF_CSTART (OFF_IDX + BATCH*NPTS)            // B*32768 ints
#define OFF_ORDER  (OFF_CSTART + BATCH*RCELLS)       // B*N ints
#define OFF_BN     (OFF_ORDER + BATCH*NPTS)          // 4*64 floats
#define OFF_WP1    (OFF_BN + 256)                    // 110592 f16 = 55296 fl
#define OFF_WP2    (OFF_WP1 + 55296)
#define OFF_FT     (OFF_WP2 + 55296)                 // B*N*64 f16 = 16777216 fl
#define OFF_GA     (OFF_FT + 16777216)               // 16777216 f16 = 8388608 fl
#define OFF_GB     (OFF_GA + 8388608)

__device__ inline float waveReduceSum(float v) {
#pragma unroll
    for (int off = 32; off > 0; off >>= 1) v += __shfl_down(v, off, 64);
    return v;
}
__device__ inline float waveReduceMax(float v) {
#pragma unroll
    for (int off = 32; off > 0; off >>= 1) v = fmaxf(v, __shfl_down(v, off, 64));
    return v;
}

// ---------------- per-batch coordinate sums ----------------
__global__ __launch_bounds__(256) void k_stats_sum(const float* __restrict__ coords,
                                                   float* __restrict__ sums) {
    __shared__ float sm[3][4];
    int b = blockIdx.x >> 3, chunk = blockIdx.x & 7;
    const float* cb = coords + (size_t)b * 3 * NPTS;
    float s0 = 0.f, s1 = 0.f, s2 = 0.f;
    for (int i = threadIdx.x; i < 8192; i += 256) {
        int n = chunk * 8192 + i;
        s0 += cb[n];
        s1 += cb[n + NPTS];
        s2 += cb[n + 2 * NPTS];
    }
    s0 = waveReduceSum(s0); s1 = waveReduceSum(s1); s2 = waveReduceSum(s2);
    int lane = threadIdx.x & 63, wid = threadIdx.x >> 6;
    if (lane == 0) { sm[0][wid] = s0; sm[1][wid] = s1; sm[2][wid] = s2; }
    __syncthreads();
    if (threadIdx.x == 0) {
        atomicAdd(&sums[b * 3 + 0], sm[0][0] + sm[0][1] + sm[0][2] + sm[0][3]);
        atomicAdd(&sums[b * 3 + 1], sm[1][0] + sm[1][1] + sm[1][2] + sm[1][3]);
        atomicAdd(&sums[b * 3 + 2], sm[2][0] + sm[2][1] + sm[2][2] + sm[2][3]);
    }
}

// ---------------- per-batch max ||coord - mean|| ----------------
__global__ __launch_bounds__(256) void k_stats_max(const float* __restrict__ coords,
                                                   const float* __restrict__ sums,
                                                   unsigned int* __restrict__ scaleBits) {
    __shared__ float sm[4];
    int b = blockIdx.x >> 3, chunk = blockIdx.x & 7;
    const float* cb = coords + (size_t)b * 3 * NPTS;
    float mx = sums[b * 3 + 0] * (1.f / NPTS);
    float my = sums[b * 3 + 1] * (1.f / NPTS);
    float mz = sums[b * 3 + 2] * (1.f / NPTS);
    float m = 0.f;
    for (int i = threadIdx.x; i < 8192; i += 256) {
        int n = chunk * 8192 + i;
        float dx = cb[n] - mx, dy = cb[n + NPTS] - my, dz = cb[n + 2 * NPTS] - mz;
        m = fmaxf(m, sqrtf(dx * dx + dy * dy + dz * dz));
    }
    m = waveReduceMax(m);
    int lane = threadIdx.x & 63, wid = threadIdx.x >> 6;
    if (lane == 0) sm[wid] = m;
    __syncthreads();
    if (threadIdx.x == 0) {
        float r = fmaxf(fmaxf(sm[0], sm[1]), fmaxf(sm[2], sm[3]));
        atomicMax(&scaleBits[b], __float_as_uint(r));
    }
}

// ---------------- voxel index + int counts ----------------
__global__ __launch_bounds__(256) void k_vox_assign(const float* __restrict__ coords,
                                                    const float* __restrict__ sums,
                                                    const unsigned int* __restrict__ scaleBits,
                                                    int* __restrict__ idxb,
                                                    int* __restrict__ cnt) {
    int g = blockIdx.x * 256 + threadIdx.x;       // 0 .. B*N-1
    int b = g >> 16, n = g & (NPTS - 1);
    const float* cb = coords + (size_t)b * 3 * NPTS;
    float scale2 = __uint_as_float(scaleBits[b]) * 2.f;
    int v[3];
#pragma unroll
    for (int d = 0; d < 3; ++d) {
        float mean = sums[b * 3 + d] * (1.f / NPTS);
        float x = (cb[d * NPTS + n] - mean) / scale2 + 0.5f;
        x *= (float)RES;
        x = fminf(fmaxf(x, 0.f), (float)(RES - 1));
        v[d] = (int)rintf(x);
    }
    int id = (v[0] * RES + v[1]) * RES + v[2];
    idxb[b * NPTS + n] = id;
    atomicAdd(&cnt[b * RCELLS + id], 1);
}

// ---------------- per-batch exclusive prefix scan of cell counts ------------
__global__ __launch_bounds__(256) void k_scan(const int* __restrict__ cnt,
                                              int* __restrict__ cellStart) {
    __shared__ int bufA[256], bufB[256];
    int b = blockIdx.x, tid = threadIdx.x;
    const int* cb = cnt + b * RCELLS;
    int sum = 0;
    for (int i = 0; i < 128; ++i) sum += cb[tid * 128 + i];
    bufA[tid] = sum;
    __syncthreads();
    int* src = bufA; int* dst = bufB;
    for (int off = 1; off < 256; off <<= 1) {
        int v = src[tid];
        if (tid >= off) v += src[tid - off];
        dst[tid] = v;
        __syncthreads();
        int* t = src; src = dst; dst = t;
    }
    int run = (tid > 0) ? src[tid - 1] : 0;        // exclusive
    int* cs = cellStart + b * RCELLS;
    for (int i = 0; i < 128; ++i) {
        int c = cb[tid * 128 + i];
        cs[tid * 128 + i] = run;
        run += c;
    }
}

// ---------------- rank points into cell-sorted order ----------------
// Mutates cellStart: afterwards cellStart[c] == end offset of cell c.
__global__ __launch_bounds__(256) void k_rank(const int* __restrict__ idxb,
                                              int* __restrict__ cellStart,
                                              int* __restrict__ order) {
    int g = blockIdx.x * 256 + threadIdx.x;
    int b = g >> 16, n = g & (NPTS - 1);
    int cell = idxb[b * NPTS + n];
    int pos = atomicAdd(&cellStart[b * RCELLS + cell], 1);
    order[b * NPTS + pos] = n;
}

// ---------------- features fp32 [b][c][n] -> f16 [b][n][64] ----------------
__global__ __launch_bounds__(256) void k_transpose(const float* __restrict__ f,
                                                   _Float16* __restrict__ featT) {
    int g = blockIdx.x * 256 + threadIdx.x;        // 0 .. B*N-1
    int b = g >> 16, n = g & (NPTS - 1);
    const float* fb = f + (size_t)b * CH * NPTS + n;
    _Float16* dst = featT + (size_t)g * 64;
#pragma unroll
    for (int k = 0; k < 8; ++k) {
        f16x8 hv;
#pragma unroll
        for (int j = 0; j < 8; ++j)
            hv[j] = (_Float16)fb[(size_t)(k * 8 + j) * NPTS];
        *(f16x8*)(dst + k * 8) = hv;
    }
}

// ---------------- gather-average into f16 channels-last grid ----------------
// gA layout: [b][ct(2)][cell][32] f16.
// GSPLIT=4 lanes cooperate per (cell, ct): each accumulates a contiguous
// quarter of the cell's points (8-pt MLP unrolled), combined via shfl_xor.
// Block swizzle: bi = chunk*8 + b, so the 8 batches' copies of a hot (x,y)
// column are consecutive blocks -> spread across CUs instead of aliasing.
__global__ __launch_bounds__(256) void k_gather(const _Float16* __restrict__ featT,
                                                const int* __restrict__ order,
                                                const int* __restrict__ cellStart,
                                                const int* __restrict__ cnt,
                                                _Float16* __restrict__ gA) {
    int bi = blockIdx.x;                  // 0 .. B*RCELLS*2*GSPLIT/256 - 1
    int b  = bi & 7;
    int chunk = bi >> 3;                  // (x,y) column id, 0..1023
    int r  = chunk * 256 + threadIdx.x;   // 0 .. RCELLS*2*GSPLIT-1
    int sub  = r & (GSPLIT - 1);
    int ct   = (r >> 2) & 1;
    int cell = r >> 3;

    int e0 = cellStart[b * RCELLS + cell];         // post-rank: end offset
    int c  = cnt[b * RCELLS + cell];
    int s0 = e0 - c;
    int len = (c + GSPLIT - 1) >> 2;
    int s = s0 + sub * len;
    int e = min(s + len, e0);

    float acc[32];
#pragma unroll
    for (int j = 0; j < 32; ++j) acc[j] = 0.f;
    const int* ob = order + b * NPTS;
    const _Float16* fb = featT + (((size_t)b << 16)) * 64 + ct * 32;

    int p = s;
    for (; p + 8 <= e; p += 8) {
        int n[8];
#pragma unroll
        for (int u = 0; u < 8; ++u) n[u] = ob[p + u];   // 8 independent loads
        f16x8 v[8][4];
#pragma unroll
        for (int u = 0; u < 8; ++u) {
            const _Float16* q = fb + (size_t)n[u] * 64;
#pragma unroll
            for (int k = 0; k < 4; ++k)
                v[u][k] = *(const f16x8*)(q + k * 8);   // 32 loads in flight
        }
#pragma unroll
        for (int u = 0; u < 8; ++u)
#pragma unroll
            for (int k = 0; k < 4; ++k)
#pragma unroll
                for (int j = 0; j < 8; ++j)
                    acc[k * 8 + j] += (float)v[u][k][j];
    }
    for (; p < e; ++p) {
        int n = ob[p];
        const _Float16* q = fb + (size_t)n * 64;
#pragma unroll
        for (int k = 0; k < 4; ++k) {
            f16x8 vv = *(const f16x8*)(q + k * 8);
#pragma unroll
            for (int j = 0; j < 8; ++j)
                acc[k * 8 + j] += (float)vv[j];
        }
    }

    // combine the 4 point-split partial sums (lanes 4t..4t+3)
#pragma unroll
    for (int j = 0; j < 32; ++j) {
        acc[j] += __shfl_xor(acc[j], 1, 64);
        acc[j] += __shfl_xor(acc[j], 2, 64);
    }

    if (sub == 0) {
        float inv = 1.f / (float)max(c, 1);
        _Float16* dst = gA + ((size_t)(b * 2 + ct) * RCELLS + cell) * 32;
#pragma unroll
        for (int k = 0; k < 4; ++k) {
            f16x8 hv;
#pragma unroll
            for (int j = 0; j < 8; ++j)
                hv[j] = (_Float16)(acc[k * 8 + j] * inv);
            *(f16x8*)(dst + k * 8) = hv;
        }
    }
}

// ---------------- weight repack (f16, MFMA A-layout) + BN constants ----------
__global__ __launch_bounds__(256) void k_prep(const float* __restrict__ w,
                                              const float* __restrict__ bias,
                                              const float* __restrict__ g,
                                              const float* __restrict__ be,
                                              const float* __restrict__ m,
                                              const float* __restrict__ v,
                                              _Float16* __restrict__ wP,
                                              float* __restrict__ bnA,
                                              float* __restrict__ bnB) {
    int s = blockIdx.x * 256 + threadIdx.x;       // 0 .. 110591
    int ci_in = s & 31;
    int t  = s >> 5;
    int co = t & 63;
    int tc = t >> 6;                               // tap*2 + ct
    int ct = tc & 1;
    int tap = tc >> 1;
    int ci = ct * 32 + ci_in;
    wP[s] = (_Float16)w[co * 1728 + ci * 27 + tap];
    if (s < 64) {
        float A = g[s] / sqrtf(v[s] + BN_EPS);
        bnA[s] = A;
        bnB[s] = (bias[s] - m[s]) * A + be[s];
    }
}

// ---------------- 3x3x3 conv via f16 MFMA (implicit shift-GEMM) -------------
__global__ __launch_bounds__(256, 2) void k_conv(const _Float16* __restrict__ gIn,
                                                 _Float16* __restrict__ gOut,
                                                 const _Float16* __restrict__ wP,
                                                 const float* __restrict__ bnA,
                                                 const float* __restrict__ bnB) {
    __shared__ _Float16 sIn[3 * 10 * 34 * 32];     // 65280 B, halo-padded
    int bi = blockIdx.x;
    int b  = bi >> 7;
    int rem = bi & 127;
    int z  = rem >> 2;
    int yg = rem & 3;
    int tid = threadIdx.x;
    int wid = tid >> 6;
    int lane = tid & 63;
    int l15 = lane & 15, quad = lane >> 4;

    f32x4 acc[4][4];
#pragma unroll
    for (int mt = 0; mt < 4; ++mt)
#pragma unroll
        for (int nt = 0; nt < 4; ++nt) acc[mt][nt] = (f32x4){0.f, 0.f, 0.f, 0.f};

    const f16x8* wp8 = (const f16x8*)wP;

    int bbase[4];
#pragma unroll
    for (int nt = 0; nt < 4; ++nt) {
        int yl = 2 * wid + (nt >> 1);
        int x  = ((nt & 1) << 4) + l15;
        bbase[nt] = ((10 + (yl + 1)) * 34 + (x + 1)) * 32 + quad * 8; // zz=1
    }

    for (int ct = 0; ct < 2; ++ct) {
        const _Float16* gin = gIn + (size_t)(b * 2 + ct) * (RCELLS * 32);
#pragma unroll
        for (int it = 0; it < 16; ++it) {
            int s = tid + it * 256;                 // 16B chunk id
            if (s < 4080) {
                int cc  = s & 3;
                int pos = s >> 2;                   // 0..1019
                int xx  = pos % 34;
                int t2  = pos / 34;
                int yy  = t2 % 10;
                int zz  = t2 / 10;
                int x = xx - 1, y = yg * 8 + yy - 1, z0 = z + zz - 1;
                f32x4 val = {0.f, 0.f, 0.f, 0.f};
                if ((unsigned)x < 32u && (unsigned)y < 32u && (unsigned)z0 < 32u)
                    val = *(const f32x4*)(gin + ((size_t)((z0 * 32 + y) * 32 + x)) * 32 + cc * 8);
                *(f32x4*)(sIn + (size_t)s * 8) = val;
            }
        }
        __syncthreads();

#pragma unroll
        for (int dz = -1; dz <= 1; ++dz)
#pragma unroll
        for (int dy = -1; dy <= 1; ++dy)
#pragma unroll
        for (int dx = -1; dx <= 1; ++dx) {
            int tap = (dz + 1) * 9 + (dy + 1) * 3 + (dx + 1);
            f16x8 aF[4];
#pragma unroll
            for (int mt = 0; mt < 4; ++mt)
                aF[mt] = wp8[tap * 512 + ct * 256 + mt * 64 + l15 * 4 + quad];
            f16x8 bF[4];
            int off = ((dz + 1) * 340 + dy * 34 + dx) * 32 - 340 * 32;
#pragma unroll
            for (int nt = 0; nt < 4; ++nt)
                bF[nt] = *(const f16x8*)(sIn + bbase[nt] + off);
#pragma unroll
            for (int mt = 0; mt < 4; ++mt)
#pragma unroll
                for (int nt = 0; nt < 4; ++nt)
                    acc[mt][nt] = __builtin_amdgcn_mfma_f32_16x16x32_f16(
                        aF[mt], bF[nt], acc[mt][nt], 0, 0, 0);
        }
        __syncthreads();
    }

#pragma unroll
    for (int nt = 0; nt < 4; ++nt) {
        int y = yg * 8 + 2 * wid + (nt >> 1);
        int x = ((nt & 1) << 4) + l15;
        int cell = z * 1024 + y * 32 + x;
#pragma unroll
        for (int mt = 0; mt < 4; ++mt) {
            int cob = mt * 16 + quad * 4;           // 4 consecutive co
            f32x4 An = *(const f32x4*)(bnA + cob);
            f32x4 Bn = *(const f32x4*)(bnB + cob);
            f16x4 hv;
#pragma unroll
            for (int r = 0; r < 4; ++r) {
                float t = acc[mt][nt][r] * An[r] + Bn[r];
                t = (t >= 0.f) ? t : NEG_SLOPE * t;
                hv[r] = (_Float16)t;
            }
            _Float16* op = gOut + ((size_t)(b * 2 + (cob >> 5)) * RCELLS + cell) * 32 + (cob & 31);
            *(f16x4*)op = hv;
        }
    }
}

// ---------------- trilinear devoxelize (recomputes norm coords) -------------
__global__ __launch_bounds__(256) void k_devox(const _Float16* __restrict__ gA,
                                               const float* __restrict__ coords,
                                               const float* __restrict__ sums,
                                               const unsigned int* __restrict__ scaleBits,
                                               float* __restrict__ out) {
    int g = blockIdx.x * 256 + threadIdx.x;        // 0 .. B*N-1
    int b = g >> 16, n = g & (NPTS - 1);
    const float* cb = coords + (size_t)b * 3 * NPTS;
    float scale2 = __uint_as_float(scaleBits[b]) * 2.f;
    float nc[3];
#pragma unroll
    for (int d = 0; d < 3; ++d) {
        float mean = sums[b * 3 + d] * (1.f / NPTS);
        float x = (cb[d * NPTS + n] - mean) / scale2 + 0.5f;
        x *= (float)RES;
        nc[d] = fminf(fmaxf(x, 0.f), (float)(RES - 1));
    }
    float tx = nc[0], ty = nc[1], tz = nc[2];
    float lx = floorf(tx), ly = floorf(ty), lz = floorf(tz);
    float fx = tx - lx, fy = ty - ly, fz = tz - lz;
    int x0 = (int)lx, y0 = (int)ly, z0 = (int)lz;
    int x1 = min(x0 + 1, RES - 1), y1 = min(y0 + 1, RES - 1), z1 = min(z0 + 1, RES - 1);
    int ids[8];
    float wc[8];
    ids[0] = (x0 * RES + y0) * RES + z0;
    ids[1] = (x0 * RES + y0) * RES + z1;
    ids[2] = (x0 * RES + y1) * RES + z0;
    ids[3] = (x0 * RES + y1) * RES + z1;
    ids[4] = (x1 * RES + y0) * RES + z0;
    ids[5] = (x1 * RES + y0) * RES + z1;
    ids[6] = (x1 * RES + y1) * RES + z0;
    ids[7] = (x1 * RES + y1) * RES + z1;
    float gx = 1.f - fx, gy = 1.f - fy, gz = 1.f - fz;
    wc[0] = gx * gy * gz; wc[1] = gx * gy * fz;
    wc[2] = gx * fy * gz; wc[3] = gx * fy * fz;
    wc[4] = fx * gy * gz; wc[5] = fx * gy * fz;
    wc[6] = fx * fy * gz; wc[7] = fx * fy * fz;

#pragma unroll
    for (int ct = 0; ct < 2; ++ct) {
        float acc[32];
#pragma unroll
        for (int j = 0; j < 32; ++j) acc[j] = 0.f;
        const _Float16* gb = gA + (size_t)(b * 2 + ct) * RCELLS * 32;
#pragma unroll
        for (int c8 = 0; c8 < 8; ++c8) {
            const _Float16* p = gb + (size_t)ids[c8] * 32;
            float wgt = wc[c8];
#pragma unroll
            for (int k = 0; k < 4; ++k) {
                f16x8 v = *(const f16x8*)(p + k * 8);
#pragma unroll
                for (int j = 0; j < 8; ++j)
                    acc[k * 8 + j] += wgt * (float)v[j];
            }
        }
        float* ob = out + (size_t)b * CH * NPTS + (size_t)(ct * 32) * NPTS + n;
#pragma unroll
        for (int j = 0; j < 32; ++j)
            ob[(size_t)j * NPTS] = acc[j];
    }
}

extern "C" void kernel_launch(void* const* d_in, const int* in_sizes, int n_in,
                              void* d_out, int out_size, void* d_ws, size_t ws_size,
                              hipStream_t stream) {
    const float* features = (const float*)d_in[0];
    const float* coords   = (const float*)d_in[1];
    const float* w1  = (const float*)d_in[2];
    const float* b1  = (const float*)d_in[3];
    const float* g1  = (const float*)d_in[4];
    const float* be1 = (const float*)d_in[5];
    const float* m1  = (const float*)d_in[6];
    const float* v1  = (const float*)d_in[7];
    const float* w2  = (const float*)d_in[8];
    const float* b2  = (const float*)d_in[9];
    const float* g2  = (const float*)d_in[10];
    const float* be2 = (const float*)d_in[11];
    const float* m2  = (const float*)d_in[12];
    const float* v2  = (const float*)d_in[13];

    float* ws = (float*)d_ws;
    float*        sums      = ws + OFF_SUMS;
    unsigned int* scaleBits = (unsigned int*)(ws + OFF_SCALE);
    int*          cnt       = (int*)(ws + OFF_CNT);
    int*          idxb      = (int*)(ws + OFF_IDX);
    int*          cellStart = (int*)(ws + OFF_CSTART);
    int*          order     = (int*)(ws + OFF_ORDER);
    float*        bnA1      = ws + OFF_BN;
    float*        bnB1      = ws + OFF_BN + 64;
    float*        bnA2      = ws + OFF_BN + 128;
    float*        bnB2      = ws + OFF_BN + 192;
    _Float16*     wP1       = (_Float16*)(ws + OFF_WP1);
    _Float16*     wP2       = (_Float16*)(ws + OFF_WP2);
    _Float16*     featT     = (_Float16*)(ws + OFF_FT);
    _Float16*     gA        = (_Float16*)(ws + OFF_GA);
    _Float16*     gB        = (_Float16*)(ws + OFF_GB);

    // zero: sums + scaleBits + cnt
    (void)hipMemsetAsync(ws, 0, (size_t)(OFF_IDX) * sizeof(float), stream);

    k_stats_sum<<<64, 256, 0, stream>>>(coords, sums);
    k_stats_max<<<64, 256, 0, stream>>>(coords, sums, scaleBits);
    k_vox_assign<<<(BATCH * NPTS) / 256, 256, 0, stream>>>(coords, sums, scaleBits,
                                                           idxb, cnt);
    k_scan<<<BATCH, 256, 0, stream>>>(cnt, cellStart);
    k_rank<<<(BATCH * NPTS) / 256, 256, 0, stream>>>(idxb, cellStart, order);
    k_transpose<<<(BATCH * NPTS) / 256, 256, 0, stream>>>(features, featT);
    k_gather<<<(BATCH * RCELLS * 2 * GSPLIT) / 256, 256, 0, stream>>>(
        featT, order, cellStart, cnt, gA);
    k_prep<<<432, 256, 0, stream>>>(w1, b1, g1, be1, m1, v1, wP1, bnA1, bnB1);
    k_prep<<<432, 256, 0, stream>>>(w2, b2, g2, be2, m2, v2, wP2, bnA2, bnB2);
    k_conv<<<BATCH * RES * 4, 256, 0, stream>>>(gA, gB, wP1, bnA1, bnB1);
    k_conv<<<BATCH * RES * 4, 256, 0, stream>>>(gB, gA, wP2, bnA2, bnB2);
    k_devox<<<(BATCH * NPTS) / 256, 256, 0, stream>>>(gA, coords, sums, scaleBits,
                                                      (float*)d_out);

    // append passthrough coords
    (void)hipMemcpyAsync((float*)d_out + (size_t)BATCH * CH * NPTS, coords,
                         (size_t)BATCH * 3 * NPTS * sizeof(float),
                         hipMemcpyDeviceToDevice, stream);
}

// Round 5
// 718.158 us; speedup vs baseline: 2.2394x; 1.0062x over previous
//
#include <hip/hip_runtime.h>
#include <hip/hip_bf16.h>
#include <hip/hip_fp16.h>

// Problem constants
#define NPTS   65536
#define BATCH  8
#define CH     64
#define RES    32
#define RCELLS 32768          // 32^3
#define NEG_SLOPE 0.1f
#define BN_EPS 1e-4f
#define GSPLIT 4              // point-parallel lanes per (cell, ct)

typedef float    f32x4 __attribute__((ext_vector_type(4)));
typedef _Float16 f16x8 __attribute__((ext_vector_type(8)));
typedef _Float16 f16x4 __attribute__((ext_vector_type(4)));

// Workspace layout (float offsets)
#define OFF_SUMS   0                                 // 24 floats
#define OFF_SCALE  24                                // 8 uints
#define OFF_CNT    32                                // B*32768 ints (zeroed)
#define OFF_IDX    (OFF_CNT + BATCH*RCELLS)          // B*N ints
#define OFF_CSTART (OFF_IDX + BATCH*NPTS)            // B*32768 ints
#define OFF_ORDER  (OFF_CSTART + BATCH*RCELLS)       // B*N ints
#define OFF_BN     (OFF_ORDER + BATCH*NPTS)          // 4*64 floats
#define OFF_WP1    (OFF_BN + 256)                    // 110592 f16 = 55296 fl
#define OFF_WP2    (OFF_WP1 + 55296)
#define OFF_FT     (OFF_WP2 + 55296)                 // B*N*64 f16 = 16777216 fl
#define OFF_GA     (OFF_FT + 16777216)               // 16777216 f16 = 8388608 fl
#define OFF_GB     (OFF_GA + 8388608)

__device__ inline float waveReduceSum(float v) {
#pragma unroll
    for (int off = 32; off > 0; off >>= 1) v += __shfl_down(v, off, 64);
    return v;
}
__device__ inline float waveReduceMax(float v) {
#pragma unroll
    for (int off = 32; off > 0; off >>= 1) v = fmaxf(v, __shfl_down(v, off, 64));
    return v;
}

// ---------------- per-batch coordinate sums ----------------
__global__ __launch_bounds__(256) void k_stats_sum(const float* __restrict__ coords,
                                                   float* __restrict__ sums) {
    __shared__ float sm[3][4];
    int b = blockIdx.x >> 3, chunk = blockIdx.x & 7;
    const float* cb = coords + (size_t)b * 3 * NPTS;
    float s0 = 0.f, s1 = 0.f, s2 = 0.f;
    for (int i = threadIdx.x; i < 8192; i += 256) {
        int n = chunk * 8192 + i;
        s0 += cb[n];
        s1 += cb[n + NPTS];
        s2 += cb[n + 2 * NPTS];
    }
    s0 = waveReduceSum(s0); s1 = waveReduceSum(s1); s2 = waveReduceSum(s2);
    int lane = threadIdx.x & 63, wid = threadIdx.x >> 6;
    if (lane == 0) { sm[0][wid] = s0; sm[1][wid] = s1; sm[2][wid] = s2; }
    __syncthreads();
    if (threadIdx.x == 0) {
        atomicAdd(&sums[b * 3 + 0], sm[0][0] + sm[0][1] + sm[0][2] + sm[0][3]);
        atomicAdd(&sums[b * 3 + 1], sm[1][0] + sm[1][1] + sm[1][2] + sm[1][3]);
        atomicAdd(&sums[b * 3 + 2], sm[2][0] + sm[2][1] + sm[2][2] + sm[2][3]);
    }
}

// ---------------- per-batch max ||coord - mean|| ----------------
__global__ __launch_bounds__(256) void k_stats_max(const float* __restrict__ coords,
                                                   const float* __restrict__ sums,
                                                   unsigned int* __restrict__ scaleBits) {
    __shared__ float sm[4];
    int b = blockIdx.x >> 3, chunk = blockIdx.x & 7;
    const float* cb = coords + (size_t)b * 3 * NPTS;
    float mx = sums[b * 3 + 0] * (1.f / NPTS);
    float my = sums[b * 3 + 1] * (1.f / NPTS);
    float mz = sums[b * 3 + 2] * (1.f / NPTS);
    float m = 0.f;
    for (int i = threadIdx.x; i < 8192; i += 256) {
        int n = chunk * 8192 + i;
        float dx = cb[n] - mx, dy = cb[n + NPTS] - my, dz = cb[n + 2 * NPTS] - mz;
        m = fmaxf(m, sqrtf(dx * dx + dy * dy + dz * dz));
    }
    m = waveReduceMax(m);
    int lane = threadIdx.x & 63, wid = threadIdx.x >> 6;
    if (lane == 0) sm[wid] = m;
    __syncthreads();
    if (threadIdx.x == 0) {
        float r = fmaxf(fmaxf(sm[0], sm[1]), fmaxf(sm[2], sm[3]));
        atomicMax(&scaleBits[b], __float_as_uint(r));
    }
}

// ---------------- voxel index + int counts ----------------
__global__ __launch_bounds__(256) void k_vox_assign(const float* __restrict__ coords,
                                                    const float* __restrict__ sums,
                                                    const unsigned int* __restrict__ scaleBits,
                                                    int* __restrict__ idxb,
                                                    int* __restrict__ cnt) {
    int g = blockIdx.x * 256 + threadIdx.x;       // 0 .. B*N-1
    int b = g >> 16, n = g & (NPTS - 1);
    const float* cb = coords + (size_t)b * 3 * NPTS;
    float scale2 = __uint_as_float(scaleBits[b]) * 2.f;
    int v[3];
#pragma unroll
    for (int d = 0; d < 3; ++d) {
        float mean = sums[b * 3 + d] * (1.f / NPTS);
        float x = (cb[d * NPTS + n] - mean) / scale2 + 0.5f;
        x *= (float)RES;
        x = fminf(fmaxf(x, 0.f), (float)(RES - 1));
        v[d] = (int)rintf(x);
    }
    int id = (v[0] * RES + v[1]) * RES + v[2];
    idxb[b * NPTS + n] = id;
    atomicAdd(&cnt[b * RCELLS + id], 1);
}

// ---------------- per-batch exclusive prefix scan of cell counts ------------
__global__ __launch_bounds__(256) void k_scan(const int* __restrict__ cnt,
                                              int* __restrict__ cellStart) {
    __shared__ int bufA[256], bufB[256];
    int b = blockIdx.x, tid = threadIdx.x;
    const int* cb = cnt + b * RCELLS;
    int sum = 0;
    for (int i = 0; i < 128; ++i) sum += cb[tid * 128 + i];
    bufA[tid] = sum;
    __syncthreads();
    int* src = bufA; int* dst = bufB;
    for (int off = 1; off < 256; off <<= 1) {
        int v = src[tid];
        if (tid >= off) v += src[tid - off];
        dst[tid] = v;
        __syncthreads();
        int* t = src; src = dst; dst = t;
    }
    int run = (tid > 0) ? src[tid - 1] : 0;        // exclusive
    int* cs = cellStart + b * RCELLS;
    for (int i = 0; i < 128; ++i) {
        int c = cb[tid * 128 + i];
        cs[tid * 128 + i] = run;
        run += c;
    }
}

// ---------------- rank points into cell-sorted order ----------------
// Mutates cellStart: afterwards cellStart[c] == end offset of cell c.
__global__ __launch_bounds__(256) void k_rank(const int* __restrict__ idxb,
                                              int* __restrict__ cellStart,
                                              int* __restrict__ order) {
    int g = blockIdx.x * 256 + threadIdx.x;
    int b = g >> 16, n = g & (NPTS - 1);
    int cell = idxb[b * NPTS + n];
    int pos = atomicAdd(&cellStart[b * RCELLS + cell], 1);
    order[b * NPTS + pos] = n;
}

// ---------------- features fp32 [b][c][n] -> f16 [b][n][64] ----------------
__global__ __launch_bounds__(256) void k_transpose(const float* __restrict__ f,
                                                   _Float16* __restrict__ featT) {
    int g = blockIdx.x * 256 + threadIdx.x;        // 0 .. B*N-1
    int b = g >> 16, n = g & (NPTS - 1);
    const float* fb = f + (size_t)b * CH * NPTS + n;
    _Float16* dst = featT + (size_t)g * 64;
#pragma unroll
    for (int k = 0; k < 8; ++k) {
        f16x8 hv;
#pragma unroll
        for (int j = 0; j < 8; ++j)
            hv[j] = (_Float16)fb[(size_t)(k * 8 + j) * NPTS];
        *(f16x8*)(dst + k * 8) = hv;
    }
}

// ---------------- gather-average into f16 channels-last grid ----------------
// gA layout: [b][ct(2)][cell][32] f16.
// GSPLIT=4 lanes cooperate per (cell, ct): each accumulates a contiguous
// quarter of the cell's points (8-pt MLP unrolled), combined via shfl_xor.
// Block swizzle: bi = chunk*8 + b, so the 8 batches' copies of a hot (x,y)
// column are consecutive blocks -> spread across CUs instead of aliasing.
__global__ __launch_bounds__(256) void k_gather(const _Float16* __restrict__ featT,
                                                const int* __restrict__ order,
                                                const int* __restrict__ cellStart,
                                                const int* __restrict__ cnt,
                                                _Float16* __restrict__ gA) {
    int bi = blockIdx.x;                  // 0 .. B*RCELLS*2*GSPLIT/256 - 1
    int b  = bi & 7;
    int chunk = bi >> 3;                  // (x,y) column id, 0..1023
    int r  = chunk * 256 + threadIdx.x;   // 0 .. RCELLS*2*GSPLIT-1
    int sub  = r & (GSPLIT - 1);
    int ct   = (r >> 2) & 1;
    int cell = r >> 3;

    int e0 = cellStart[b * RCELLS + cell];         // post-rank: end offset
    int c  = cnt[b * RCELLS + cell];
    int s0 = e0 - c;
    int len = (c + GSPLIT - 1) >> 2;
    int s = s0 + sub * len;
    int e = min(s + len, e0);

    float acc[32];
#pragma unroll
    for (int j = 0; j < 32; ++j) acc[j] = 0.f;
    const int* ob = order + b * NPTS;
    const _Float16* fb = featT + (((size_t)b << 16)) * 64 + ct * 32;

    int p = s;
    for (; p + 8 <= e; p += 8) {
        int n[8];
#pragma unroll
        for (int u = 0; u < 8; ++u) n[u] = ob[p + u];   // 8 independent loads
        f16x8 v[8][4];
#pragma unroll
        for (int u = 0; u < 8; ++u) {
            const _Float16* q = fb + (size_t)n[u] * 64;
#pragma unroll
            for (int k = 0; k < 4; ++k)
                v[u][k] = *(const f16x8*)(q + k * 8);   // 32 loads in flight
        }
#pragma unroll
        for (int u = 0; u < 8; ++u)
#pragma unroll
            for (int k = 0; k < 4; ++k)
#pragma unroll
                for (int j = 0; j < 8; ++j)
                    acc[k * 8 + j] += (float)v[u][k][j];
    }
    for (; p < e; ++p) {
        int n = ob[p];
        const _Float16* q = fb + (size_t)n * 64;
#pragma unroll
        for (int k = 0; k < 4; ++k) {
            f16x8 vv = *(const f16x8*)(q + k * 8);
#pragma unroll
            for (int j = 0; j < 8; ++j)
                acc[k * 8 + j] += (float)vv[j];
        }
    }

    // combine the 4 point-split partial sums (lanes 4t..4t+3)
#pragma unroll
    for (int j = 0; j < 32; ++j) {
        acc[j] += __shfl_xor(acc[j], 1, 64);
        acc[j] += __shfl_xor(acc[j], 2, 64);
    }

    if (sub == 0) {
        float inv = 1.f / (float)max(c, 1);
        _Float16* dst = gA + ((size_t)(b * 2 + ct) * RCELLS + cell) * 32;
#pragma unroll
        for (int k = 0; k < 4; ++k) {
            f16x8 hv;
#pragma unroll
            for (int j = 0; j < 8; ++j)
                hv[j] = (_Float16)(acc[k * 8 + j] * inv);
            *(f16x8*)(dst + k * 8) = hv;
        }
    }
}

// ---------------- weight repack (f16, MFMA A-layout) + BN constants ----------
__global__ __launch_bounds__(256) void k_prep(const float* __restrict__ w,
                                              const float* __restrict__ bias,
                                              const float* __restrict__ g,
                                              const float* __restrict__ be,
                                              const float* __restrict__ m,
                                              const float* __restrict__ v,
                                              _Float16* __restrict__ wP,
                                              float* __restrict__ bnA,
                                              float* __restrict__ bnB) {
    int s = blockIdx.x * 256 + threadIdx.x;       // 0 .. 110591
    int ci_in = s & 31;
    int t  = s >> 5;
    int co = t & 63;
    int tc = t >> 6;                               // tap*2 + ct
    int ct = tc & 1;
    int tap = tc >> 1;
    int ci = ct * 32 + ci_in;
    wP[s] = (_Float16)w[co * 1728 + ci * 27 + tap];
    if (s < 64) {
        float A = g[s] / sqrtf(v[s] + BN_EPS);
        bnA[s] = A;
        bnB[s] = (bias[s] - m[s]) * A + be[s];
    }
}

// ---------------- 3x3x3 conv via f16 MFMA (implicit shift-GEMM) -------------
__global__ __launch_bounds__(256, 2) void k_conv(const _Float16* __restrict__ gIn,
                                                 _Float16* __restrict__ gOut,
                                                 const _Float16* __restrict__ wP,
                                                 const float* __restrict__ bnA,
                                                 const float* __restrict__ bnB) {
    __shared__ _Float16 sIn[3 * 10 * 34 * 32];     // 65280 B, halo-padded
    int bi = blockIdx.x;
    int b  = bi >> 7;
    int rem = bi & 127;
    int z  = rem >> 2;
    int yg = rem & 3;
    int tid = threadIdx.x;
    int wid = tid >> 6;
    int lane = tid & 63;
    int l15 = lane & 15, quad = lane >> 4;

    f32x4 acc[4][4];
#pragma unroll
    for (int mt = 0; mt < 4; ++mt)
#pragma unroll
        for (int nt = 0; nt < 4; ++nt) acc[mt][nt] = (f32x4){0.f, 0.f, 0.f, 0.f};

    const f16x8* wp8 = (const f16x8*)wP;

    int bbase[4];
#pragma unroll
    for (int nt = 0; nt < 4; ++nt) {
        int yl = 2 * wid + (nt >> 1);
        int x  = ((nt & 1) << 4) + l15;
        bbase[nt] = ((10 + (yl + 1)) * 34 + (x + 1)) * 32 + quad * 8; // zz=1
    }

    for (int ct = 0; ct < 2; ++ct) {
        const _Float16* gin = gIn + (size_t)(b * 2 + ct) * (RCELLS * 32);
#pragma unroll
        for (int it = 0; it < 16; ++it) {
            int s = tid + it * 256;                 // 16B chunk id
            if (s < 4080) {
                int cc  = s & 3;
                int pos = s >> 2;                   // 0..1019
                int xx  = pos % 34;
                int t2  = pos / 34;
                int yy  = t2 % 10;
                int zz  = t2 / 10;
                int x = xx - 1, y = yg * 8 + yy - 1, z0 = z + zz - 1;
                f32x4 val = {0.f, 0.f, 0.f, 0.f};
                if ((unsigned)x < 32u && (unsigned)y < 32u && (unsigned)z0 < 32u)
                    val = *(const f32x4*)(gin + ((size_t)((z0 * 32 + y) * 32 + x)) * 32 + cc * 8);
                *(f32x4*)(sIn + (size_t)s * 8) = val;
            }
        }
        __syncthreads();

#pragma unroll
        for (int dz = -1; dz <= 1; ++dz)
#pragma unroll
        for (int dy = -1; dy <= 1; ++dy)
#pragma unroll
        for (int dx = -1; dx <= 1; ++dx) {
            int tap = (dz + 1) * 9 + (dy + 1) * 3 + (dx + 1);
            f16x8 aF[4];
#pragma unroll
            for (int mt = 0; mt < 4; ++mt)
                aF[mt] = wp8[tap * 512 + ct * 256 + mt * 64 + l15 * 4 + quad];
            f16x8 bF[4];
            int off = ((dz + 1) * 340 + dy * 34 + dx) * 32 - 340 * 32;
#pragma unroll
            for (int nt = 0; nt < 4; ++nt)
                bF[nt] = *(const f16x8*)(sIn + bbase[nt] + off);
#pragma unroll
            for (int mt = 0; mt < 4; ++mt)
#pragma unroll
                for (int nt = 0; nt < 4; ++nt)
                    acc[mt][nt] = __builtin_amdgcn_mfma_f32_16x16x32_f16(
                        aF[mt], bF[nt], acc[mt][nt], 0, 0, 0);
        }
        __syncthreads();
    }

#pragma unroll
    for (int nt = 0; nt < 4; ++nt) {
        int y = yg * 8 + 2 * wid + (nt >> 1);
        int x = ((nt & 1) << 4) + l15;
        int cell = z * 1024 + y * 32 + x;
#pragma unroll
        for (int mt = 0; mt < 4; ++mt) {
            int cob = mt * 16 + quad * 4;           // 4 consecutive co
            f32x4 An = *(const f32x4*)(bnA + cob);
            f32x4 Bn = *(const f32x4*)(bnB + cob);
            f16x4 hv;
#pragma unroll
            for (int r = 0; r < 4; ++r) {
                float t = acc[mt][nt][r] * An[r] + Bn[r];
                t = (t >= 0.f) ? t : NEG_SLOPE * t;
                hv[r] = (_Float16)t;
            }
            _Float16* op = gOut + ((size_t)(b * 2 + (cob >> 5)) * RCELLS + cell) * 32 + (cob & 31);
            *(f16x4*)op = hv;
        }
    }
}

// ---------------- trilinear devoxelize (recomputes norm coords) -------------
// ct split across threads: g = b(3) | ct(1) | n(16). Consecutive lanes have
// consecutive n -> coords loads and output stores stay coalesced. Halves the
// per-thread dependent chain and doubles TLP vs. the ct-loop version.
// Output stores are nontemporal (streaming, write-once) to keep gA in L2.
__global__ __launch_bounds__(256) void k_devox(const _Float16* __restrict__ gA,
                                               const float* __restrict__ coords,
                                               const float* __restrict__ sums,
                                               const unsigned int* __restrict__ scaleBits,
                                               float* __restrict__ out) {
    int g = blockIdx.x * 256 + threadIdx.x;        // 0 .. 2*B*N-1
    int b = g >> 17;
    int ct = (g >> 16) & 1;
    int n = g & (NPTS - 1);
    const float* cb = coords + (size_t)b * 3 * NPTS;
    float scale2 = __uint_as_float(scaleBits[b]) * 2.f;
    float nc[3];
#pragma unroll
    for (int d = 0; d < 3; ++d) {
        float mean = sums[b * 3 + d] * (1.f / NPTS);
        float x = (cb[d * NPTS + n] - mean) / scale2 + 0.5f;
        x *= (float)RES;
        nc[d] = fminf(fmaxf(x, 0.f), (float)(RES - 1));
    }
    float tx = nc[0], ty = nc[1], tz = nc[2];
    float lx = floorf(tx), ly = floorf(ty), lz = floorf(tz);
    float fx = tx - lx, fy = ty - ly, fz = tz - lz;
    int x0 = (int)lx, y0 = (int)ly, z0 = (int)lz;
    int x1 = min(x0 + 1, RES - 1), y1 = min(y0 + 1, RES - 1), z1 = min(z0 + 1, RES - 1);
    int ids[8];
    float wc[8];
    ids[0] = (x0 * RES + y0) * RES + z0;
    ids[1] = (x0 * RES + y0) * RES + z1;
    ids[2] = (x0 * RES + y1) * RES + z0;
    ids[3] = (x0 * RES + y1) * RES + z1;
    ids[4] = (x1 * RES + y0) * RES + z0;
    ids[5] = (x1 * RES + y0) * RES + z1;
    ids[6] = (x1 * RES + y1) * RES + z0;
    ids[7] = (x1 * RES + y1) * RES + z1;
    float gx = 1.f - fx, gy = 1.f - fy, gz = 1.f - fz;
    wc[0] = gx * gy * gz; wc[1] = gx * gy * fz;
    wc[2] = gx * fy * gz; wc[3] = gx * fy * fz;
    wc[4] = fx * gy * gz; wc[5] = fx * gy * fz;
    wc[6] = fx * fy * gz; wc[7] = fx * fy * fz;

    float acc[32];
#pragma unroll
    for (int j = 0; j < 32; ++j) acc[j] = 0.f;
    const _Float16* gb = gA + (size_t)(b * 2 + ct) * RCELLS * 32;
#pragma unroll
    for (int c8 = 0; c8 < 8; ++c8) {
        const _Float16* p = gb + (size_t)ids[c8] * 32;
        float wgt = wc[c8];
#pragma unroll
        for (int k = 0; k < 4; ++k) {
            f16x8 v = *(const f16x8*)(p + k * 8);
#pragma unroll
            for (int j = 0; j < 8; ++j)
                acc[k * 8 + j] += wgt * (float)v[j];
        }
    }
    float* ob = out + (size_t)b * CH * NPTS + (size_t)(ct * 32) * NPTS + n;
#pragma unroll
    for (int j = 0; j < 32; ++j)
        __builtin_nontemporal_store(acc[j], ob + (size_t)j * NPTS);
}

extern "C" void kernel_launch(void* const* d_in, const int* in_sizes, int n_in,
                              void* d_out, int out_size, void* d_ws, size_t ws_size,
                              hipStream_t stream) {
    const float* features = (const float*)d_in[0];
    const float* coords   = (const float*)d_in[1];
    const float* w1  = (const float*)d_in[2];
    const float* b1  = (const float*)d_in[3];
    const float* g1  = (const float*)d_in[4];
    const float* be1 = (const float*)d_in[5];
    const float* m1  = (const float*)d_in[6];
    const float* v1  = (const float*)d_in[7];
    const float* w2  = (const float*)d_in[8];
    const float* b2  = (const float*)d_in[9];
    const float* g2  = (const float*)d_in[10];
    const float* be2 = (const float*)d_in[11];
    const float* m2  = (const float*)d_in[12];
    const float* v2  = (const float*)d_in[13];

    float* ws = (float*)d_ws;
    float*        sums      = ws + OFF_SUMS;
    unsigned int* scaleBits = (unsigned int*)(ws + OFF_SCALE);
    int*          cnt       = (int*)(ws + OFF_CNT);
    int*          idxb      = (int*)(ws + OFF_IDX);
    int*          cellStart = (int*)(ws + OFF_CSTART);
    int*          order     = (int*)(ws + OFF_ORDER);
    float*        bnA1      = ws + OFF_BN;
    float*        bnB1      = ws + OFF_BN + 64;
    float*        bnA2      = ws + OFF_BN + 128;
    float*        bnB2      = ws + OFF_BN + 192;
    _Float16*     wP1       = (_Float16*)(ws + OFF_WP1);
    _Float16*     wP2       = (_Float16*)(ws + OFF_WP2);
    _Float16*     featT     = (_Float16*)(ws + OFF_FT);
    _Float16*     gA        = (_Float16*)(ws + OFF_GA);
    _Float16*     gB        = (_Float16*)(ws + OFF_GB);

    // zero: sums + scaleBits + cnt
    (void)hipMemsetAsync(ws, 0, (size_t)(OFF_IDX) * sizeof(float), stream);

    k_stats_sum<<<64, 256, 0, stream>>>(coords, sums);
    k_stats_max<<<64, 256, 0, stream>>>(coords, sums, scaleBits);
    k_vox_assign<<<(BATCH * NPTS) / 256, 256, 0, stream>>>(coords, sums, scaleBits,
                                                           idxb, cnt);
    k_scan<<<BATCH, 256, 0, stream>>>(cnt, cellStart);
    k_rank<<<(BATCH * NPTS) / 256, 256, 0, stream>>>(idxb, cellStart, order);
    k_transpose<<<(BATCH * NPTS) / 256, 256, 0, stream>>>(features, featT);
    k_gather<<<(BATCH * RCELLS * 2 * GSPLIT) / 256, 256, 0, stream>>>(
        featT, order, cellStart, cnt, gA);
    k_prep<<<432, 256, 0, stream>>>(w1, b1, g1, be1, m1, v1, wP1, bnA1, bnB1);
    k_prep<<<432, 256, 0, stream>>>(w2, b2, g2, be2, m2, v2, wP2, bnA2, bnB2);
    k_conv<<<BATCH * RES * 4, 256, 0, stream>>>(gA, gB, wP1, bnA1, bnB1);
    k_conv<<<BATCH * RES * 4, 256, 0, stream>>>(gB, gA, wP2, bnA2, bnB2);
    k_devox<<<(2 * BATCH * NPTS) / 256, 256, 0, stream>>>(gA, coords, sums, scaleBits,
                                                          (float*)d_out);

    // append passthrough coords
    (void)hipMemcpyAsync((float*)d_out + (size_t)BATCH * CH * NPTS, coords,
                         (size_t)BATCH * 3 * NPTS * sizeof(float),
                         hipMemcpyDeviceToDevice, stream);
}

// Round 6
// 692.678 us; speedup vs baseline: 2.3218x; 1.0368x over previous
//
#include <hip/hip_runtime.h>
#include <hip/hip_bf16.h>
#include <hip/hip_fp16.h>

// Problem constants
#define NPTS   65536
#define BATCH  8
#define CH     64
#define RES    32
#define RCELLS 32768          // 32^3
#define NEG_SLOPE 0.1f
#define BN_EPS 1e-4f
#define GSPLIT 4              // point-parallel lanes per (cell, ct)

typedef float    f32x4 __attribute__((ext_vector_type(4)));
typedef _Float16 f16x8 __attribute__((ext_vector_type(8)));
typedef _Float16 f16x4 __attribute__((ext_vector_type(4)));

// Workspace layout (float offsets)
#define OFF_SUMS   0                                 // 24 floats
#define OFF_SCALE  24                                // 8 uints
#define OFF_CNT    32                                // B*32768 ints (zeroed)
#define OFF_IDX    (OFF_CNT + BATCH*RCELLS)          // B*N ints
#define OFF_CSTART (OFF_IDX + BATCH*NPTS)            // B*32768 ints
#define OFF_ORDER  (OFF_CSTART + BATCH*RCELLS)       // B*N ints
#define OFF_BN     (OFF_ORDER + BATCH*NPTS)          // 4*64 floats
#define OFF_WP1    (OFF_BN + 256)                    // 110592 f16 = 55296 fl
#define OFF_WP2    (OFF_WP1 + 55296)
#define OFF_FT     (OFF_WP2 + 55296)                 // B*N*64 f16 = 16777216 fl
#define OFF_GA     (OFF_FT + 16777216)               // 16777216 f16 = 8388608 fl
#define OFF_GB     (OFF_GA + 8388608)
// devox meta (float4 per point, 8 MB) reuses the featT area (free after gather)
#define OFF_META   OFF_FT

__device__ inline float waveReduceSum(float v) {
#pragma unroll
    for (int off = 32; off > 0; off >>= 1) v += __shfl_down(v, off, 64);
    return v;
}
__device__ inline float waveReduceMax(float v) {
#pragma unroll
    for (int off = 32; off > 0; off >>= 1) v = fmaxf(v, __shfl_down(v, off, 64));
    return v;
}

// ---------------- per-batch coordinate sums ----------------
__global__ __launch_bounds__(256) void k_stats_sum(const float* __restrict__ coords,
                                                   float* __restrict__ sums) {
    __shared__ float sm[3][4];
    int b = blockIdx.x >> 3, chunk = blockIdx.x & 7;
    const float* cb = coords + (size_t)b * 3 * NPTS;
    float s0 = 0.f, s1 = 0.f, s2 = 0.f;
    for (int i = threadIdx.x; i < 8192; i += 256) {
        int n = chunk * 8192 + i;
        s0 += cb[n];
        s1 += cb[n + NPTS];
        s2 += cb[n + 2 * NPTS];
    }
    s0 = waveReduceSum(s0); s1 = waveReduceSum(s1); s2 = waveReduceSum(s2);
    int lane = threadIdx.x & 63, wid = threadIdx.x >> 6;
    if (lane == 0) { sm[0][wid] = s0; sm[1][wid] = s1; sm[2][wid] = s2; }
    __syncthreads();
    if (threadIdx.x == 0) {
        atomicAdd(&sums[b * 3 + 0], sm[0][0] + sm[0][1] + sm[0][2] + sm[0][3]);
        atomicAdd(&sums[b * 3 + 1], sm[1][0] + sm[1][1] + sm[1][2] + sm[1][3]);
        atomicAdd(&sums[b * 3 + 2], sm[2][0] + sm[2][1] + sm[2][2] + sm[2][3]);
    }
}

// ---------------- per-batch max ||coord - mean|| ----------------
__global__ __launch_bounds__(256) void k_stats_max(const float* __restrict__ coords,
                                                   const float* __restrict__ sums,
                                                   unsigned int* __restrict__ scaleBits) {
    __shared__ float sm[4];
    int b = blockIdx.x >> 3, chunk = blockIdx.x & 7;
    const float* cb = coords + (size_t)b * 3 * NPTS;
    float mx = sums[b * 3 + 0] * (1.f / NPTS);
    float my = sums[b * 3 + 1] * (1.f / NPTS);
    float mz = sums[b * 3 + 2] * (1.f / NPTS);
    float m = 0.f;
    for (int i = threadIdx.x; i < 8192; i += 256) {
        int n = chunk * 8192 + i;
        float dx = cb[n] - mx, dy = cb[n + NPTS] - my, dz = cb[n + 2 * NPTS] - mz;
        m = fmaxf(m, sqrtf(dx * dx + dy * dy + dz * dz));
    }
    m = waveReduceMax(m);
    int lane = threadIdx.x & 63, wid = threadIdx.x >> 6;
    if (lane == 0) sm[wid] = m;
    __syncthreads();
    if (threadIdx.x == 0) {
        float r = fmaxf(fmaxf(sm[0], sm[1]), fmaxf(sm[2], sm[3]));
        atomicMax(&scaleBits[b], __float_as_uint(r));
    }
}

// ---------------- voxel index + int counts ----------------
__global__ __launch_bounds__(256) void k_vox_assign(const float* __restrict__ coords,
                                                    const float* __restrict__ sums,
                                                    const unsigned int* __restrict__ scaleBits,
                                                    int* __restrict__ idxb,
                                                    int* __restrict__ cnt) {
    int g = blockIdx.x * 256 + threadIdx.x;       // 0 .. B*N-1
    int b = g >> 16, n = g & (NPTS - 1);
    const float* cb = coords + (size_t)b * 3 * NPTS;
    float scale2 = __uint_as_float(scaleBits[b]) * 2.f;
    int v[3];
#pragma unroll
    for (int d = 0; d < 3; ++d) {
        float mean = sums[b * 3 + d] * (1.f / NPTS);
        float x = (cb[d * NPTS + n] - mean) / scale2 + 0.5f;
        x *= (float)RES;
        x = fminf(fmaxf(x, 0.f), (float)(RES - 1));
        v[d] = (int)rintf(x);
    }
    int id = (v[0] * RES + v[1]) * RES + v[2];
    idxb[b * NPTS + n] = id;
    atomicAdd(&cnt[b * RCELLS + id], 1);
}

// ---------------- per-batch exclusive prefix scan of cell counts ------------
__global__ __launch_bounds__(256) void k_scan(const int* __restrict__ cnt,
                                              int* __restrict__ cellStart) {
    __shared__ int bufA[256], bufB[256];
    int b = blockIdx.x, tid = threadIdx.x;
    const int* cb = cnt + b * RCELLS;
    int sum = 0;
    for (int i = 0; i < 128; ++i) sum += cb[tid * 128 + i];
    bufA[tid] = sum;
    __syncthreads();
    int* src = bufA; int* dst = bufB;
    for (int off = 1; off < 256; off <<= 1) {
        int v = src[tid];
        if (tid >= off) v += src[tid - off];
        dst[tid] = v;
        __syncthreads();
        int* t = src; src = dst; dst = t;
    }
    int run = (tid > 0) ? src[tid - 1] : 0;        // exclusive
    int* cs = cellStart + b * RCELLS;
    for (int i = 0; i < 128; ++i) {
        int c = cb[tid * 128 + i];
        cs[tid * 128 + i] = run;
        run += c;
    }
}

// ---------------- rank points into cell-sorted order ----------------
// Mutates cellStart: afterwards cellStart[c] == end offset of cell c.
__global__ __launch_bounds__(256) void k_rank(const int* __restrict__ idxb,
                                              int* __restrict__ cellStart,
                                              int* __restrict__ order) {
    int g = blockIdx.x * 256 + threadIdx.x;
    int b = g >> 16, n = g & (NPTS - 1);
    int cell = idxb[b * NPTS + n];
    int pos = atomicAdd(&cellStart[b * RCELLS + cell], 1);
    order[b * NPTS + pos] = n;
}

// ---------------- features fp32 [b][c][n] -> f16 [b][n][64] ----------------
__global__ __launch_bounds__(256) void k_transpose(const float* __restrict__ f,
                                                   _Float16* __restrict__ featT) {
    int g = blockIdx.x * 256 + threadIdx.x;        // 0 .. B*N-1
    int b = g >> 16, n = g & (NPTS - 1);
    const float* fb = f + (size_t)b * CH * NPTS + n;
    _Float16* dst = featT + (size_t)g * 64;
#pragma unroll
    for (int k = 0; k < 8; ++k) {
        f16x8 hv;
#pragma unroll
        for (int j = 0; j < 8; ++j)
            hv[j] = (_Float16)fb[(size_t)(k * 8 + j) * NPTS];
        *(f16x8*)(dst + k * 8) = hv;
    }
}

// ---------------- gather-average into f16 channels-last grid ----------------
// gA layout: [b][ct(2)][cell][32] f16.
// GSPLIT=4 lanes cooperate per (cell, ct): each accumulates a contiguous
// quarter of the cell's points (8-pt MLP unrolled), combined via shfl_xor.
// Block swizzle: bi = chunk*8 + b, so the 8 batches' copies of a hot (x,y)
// column are consecutive blocks -> spread across CUs instead of aliasing.
__global__ __launch_bounds__(256) void k_gather(const _Float16* __restrict__ featT,
                                                const int* __restrict__ order,
                                                const int* __restrict__ cellStart,
                                                const int* __restrict__ cnt,
                                                _Float16* __restrict__ gA) {
    int bi = blockIdx.x;                  // 0 .. B*RCELLS*2*GSPLIT/256 - 1
    int b  = bi & 7;
    int chunk = bi >> 3;                  // (x,y) column id, 0..1023
    int r  = chunk * 256 + threadIdx.x;   // 0 .. RCELLS*2*GSPLIT-1
    int sub  = r & (GSPLIT - 1);
    int ct   = (r >> 2) & 1;
    int cell = r >> 3;

    int e0 = cellStart[b * RCELLS + cell];         // post-rank: end offset
    int c  = cnt[b * RCELLS + cell];
    int s0 = e0 - c;
    int len = (c + GSPLIT - 1) >> 2;
    int s = s0 + sub * len;
    int e = min(s + len, e0);

    float acc[32];
#pragma unroll
    for (int j = 0; j < 32; ++j) acc[j] = 0.f;
    const int* ob = order + b * NPTS;
    const _Float16* fb = featT + (((size_t)b << 16)) * 64 + ct * 32;

    int p = s;
    for (; p + 8 <= e; p += 8) {
        int n[8];
#pragma unroll
        for (int u = 0; u < 8; ++u) n[u] = ob[p + u];   // 8 independent loads
        f16x8 v[8][4];
#pragma unroll
        for (int u = 0; u < 8; ++u) {
            const _Float16* q = fb + (size_t)n[u] * 64;
#pragma unroll
            for (int k = 0; k < 4; ++k)
                v[u][k] = *(const f16x8*)(q + k * 8);   // 32 loads in flight
        }
#pragma unroll
        for (int u = 0; u < 8; ++u)
#pragma unroll
            for (int k = 0; k < 4; ++k)
#pragma unroll
                for (int j = 0; j < 8; ++j)
                    acc[k * 8 + j] += (float)v[u][k][j];
    }
    for (; p < e; ++p) {
        int n = ob[p];
        const _Float16* q = fb + (size_t)n * 64;
#pragma unroll
        for (int k = 0; k < 4; ++k) {
            f16x8 vv = *(const f16x8*)(q + k * 8);
#pragma unroll
            for (int j = 0; j < 8; ++j)
                acc[k * 8 + j] += (float)vv[j];
        }
    }

    // combine the 4 point-split partial sums (lanes 4t..4t+3)
#pragma unroll
    for (int j = 0; j < 32; ++j) {
        acc[j] += __shfl_xor(acc[j], 1, 64);
        acc[j] += __shfl_xor(acc[j], 2, 64);
    }

    if (sub == 0) {
        float inv = 1.f / (float)max(c, 1);
        _Float16* dst = gA + ((size_t)(b * 2 + ct) * RCELLS + cell) * 32;
#pragma unroll
        for (int k = 0; k < 4; ++k) {
            f16x8 hv;
#pragma unroll
            for (int j = 0; j < 8; ++j)
                hv[j] = (_Float16)(acc[k * 8 + j] * inv);
            *(f16x8*)(dst + k * 8) = hv;
        }
    }
}

// ---------------- weight repack (f16, MFMA A-layout) + BN constants ----------
__global__ __launch_bounds__(256) void k_prep(const float* __restrict__ w,
                                              const float* __restrict__ bias,
                                              const float* __restrict__ g,
                                              const float* __restrict__ be,
                                              const float* __restrict__ m,
                                              const float* __restrict__ v,
                                              _Float16* __restrict__ wP,
                                              float* __restrict__ bnA,
                                              float* __restrict__ bnB) {
    int s = blockIdx.x * 256 + threadIdx.x;       // 0 .. 110591
    int ci_in = s & 31;
    int t  = s >> 5;
    int co = t & 63;
    int tc = t >> 6;                               // tap*2 + ct
    int ct = tc & 1;
    int tap = tc >> 1;
    int ci = ct * 32 + ci_in;
    wP[s] = (_Float16)w[co * 1728 + ci * 27 + tap];
    if (s < 64) {
        float A = g[s] / sqrtf(v[s] + BN_EPS);
        bnA[s] = A;
        bnB[s] = (bias[s] - m[s]) * A + be[s];
    }
}

// ---------------- 3x3x3 conv via f16 MFMA (implicit shift-GEMM) -------------
__global__ __launch_bounds__(256, 2) void k_conv(const _Float16* __restrict__ gIn,
                                                 _Float16* __restrict__ gOut,
                                                 const _Float16* __restrict__ wP,
                                                 const float* __restrict__ bnA,
                                                 const float* __restrict__ bnB) {
    __shared__ _Float16 sIn[3 * 10 * 34 * 32];     // 65280 B, halo-padded
    int bi = blockIdx.x;
    int b  = bi >> 7;
    int rem = bi & 127;
    int z  = rem >> 2;
    int yg = rem & 3;
    int tid = threadIdx.x;
    int wid = tid >> 6;
    int lane = tid & 63;
    int l15 = lane & 15, quad = lane >> 4;

    f32x4 acc[4][4];
#pragma unroll
    for (int mt = 0; mt < 4; ++mt)
#pragma unroll
        for (int nt = 0; nt < 4; ++nt) acc[mt][nt] = (f32x4){0.f, 0.f, 0.f, 0.f};

    const f16x8* wp8 = (const f16x8*)wP;

    int bbase[4];
#pragma unroll
    for (int nt = 0; nt < 4; ++nt) {
        int yl = 2 * wid + (nt >> 1);
        int x  = ((nt & 1) << 4) + l15;
        bbase[nt] = ((10 + (yl + 1)) * 34 + (x + 1)) * 32 + quad * 8; // zz=1
    }

    for (int ct = 0; ct < 2; ++ct) {
        const _Float16* gin = gIn + (size_t)(b * 2 + ct) * (RCELLS * 32);
#pragma unroll
        for (int it = 0; it < 16; ++it) {
            int s = tid + it * 256;                 // 16B chunk id
            if (s < 4080) {
                int cc  = s & 3;
                int pos = s >> 2;                   // 0..1019
                int xx  = pos % 34;
                int t2  = pos / 34;
                int yy  = t2 % 10;
                int zz  = t2 / 10;
                int x = xx - 1, y = yg * 8 + yy - 1, z0 = z + zz - 1;
                f32x4 val = {0.f, 0.f, 0.f, 0.f};
                if ((unsigned)x < 32u && (unsigned)y < 32u && (unsigned)z0 < 32u)
                    val = *(const f32x4*)(gin + ((size_t)((z0 * 32 + y) * 32 + x)) * 32 + cc * 8);
                *(f32x4*)(sIn + (size_t)s * 8) = val;
            }
        }
        __syncthreads();

#pragma unroll
        for (int dz = -1; dz <= 1; ++dz)
#pragma unroll
        for (int dy = -1; dy <= 1; ++dy)
#pragma unroll
        for (int dx = -1; dx <= 1; ++dx) {
            int tap = (dz + 1) * 9 + (dy + 1) * 3 + (dx + 1);
            f16x8 aF[4];
#pragma unroll
            for (int mt = 0; mt < 4; ++mt)
                aF[mt] = wp8[tap * 512 + ct * 256 + mt * 64 + l15 * 4 + quad];
            f16x8 bF[4];
            int off = ((dz + 1) * 340 + dy * 34 + dx) * 32 - 340 * 32;
#pragma unroll
            for (int nt = 0; nt < 4; ++nt)
                bF[nt] = *(const f16x8*)(sIn + bbase[nt] + off);
#pragma unroll
            for (int mt = 0; mt < 4; ++mt)
#pragma unroll
                for (int nt = 0; nt < 4; ++nt)
                    acc[mt][nt] = __builtin_amdgcn_mfma_f32_16x16x32_f16(
                        aF[mt], bF[nt], acc[mt][nt], 0, 0, 0);
        }
        __syncthreads();
    }

#pragma unroll
    for (int nt = 0; nt < 4; ++nt) {
        int y = yg * 8 + 2 * wid + (nt >> 1);
        int x = ((nt & 1) << 4) + l15;
        int cell = z * 1024 + y * 32 + x;
#pragma unroll
        for (int mt = 0; mt < 4; ++mt) {
            int cob = mt * 16 + quad * 4;           // 4 consecutive co
            f32x4 An = *(const f32x4*)(bnA + cob);
            f32x4 Bn = *(const f32x4*)(bnB + cob);
            f16x4 hv;
#pragma unroll
            for (int r = 0; r < 4; ++r) {
                float t = acc[mt][nt][r] * An[r] + Bn[r];
                t = (t >= 0.f) ? t : NEG_SLOPE * t;
                hv[r] = (_Float16)t;
            }
            _Float16* op = gOut + ((size_t)(b * 2 + (cob >> 5)) * RCELLS + cell) * 32 + (cob & 31);
            *(f16x4*)op = hv;
        }
    }
}

// ---------------- devox meta: per-point trilinear geometry -------------------
// meta[b*N+n] = {fx, fy, fz, bits(id0 | dx<<15 | dy<<16 | dz<<17)}
__global__ __launch_bounds__(256) void k_dprep(const float* __restrict__ coords,
                                               const float* __restrict__ sums,
                                               const unsigned int* __restrict__ scaleBits,
                                               f32x4* __restrict__ meta) {
    int g = blockIdx.x * 256 + threadIdx.x;        // 0 .. B*N-1
    int b = g >> 16, n = g & (NPTS - 1);
    const float* cb = coords + (size_t)b * 3 * NPTS;
    float scale2 = __uint_as_float(scaleBits[b]) * 2.f;
    float nc[3];
#pragma unroll
    for (int d = 0; d < 3; ++d) {
        float mean = sums[b * 3 + d] * (1.f / NPTS);
        float x = (cb[d * NPTS + n] - mean) / scale2 + 0.5f;
        x *= (float)RES;
        nc[d] = fminf(fmaxf(x, 0.f), (float)(RES - 1));
    }
    float lx = floorf(nc[0]), ly = floorf(nc[1]), lz = floorf(nc[2]);
    int x0 = (int)lx, y0 = (int)ly, z0 = (int)lz;
    int dx = (x0 + 1 <= RES - 1) ? 1 : 0;
    int dy = (y0 + 1 <= RES - 1) ? 1 : 0;
    int dz = (z0 + 1 <= RES - 1) ? 1 : 0;
    int id0 = (x0 * RES + y0) * RES + z0;
    int pk = id0 | (dx << 15) | (dy << 16) | (dz << 17);
    f32x4 m;
    m[0] = nc[0] - lx; m[1] = nc[1] - ly; m[2] = nc[2] - lz;
    m[3] = __int_as_float(pk);
    meta[(size_t)b * NPTS + n] = m;
}

// ---------------- trilinear devoxelize (wave-cooperative) -------------------
// Wave = 16 points x 4 chunks (lane = chunk*16 + psub); corner is the loop
// variable. Each load instruction covers 16 corner-rows (64B each) with 4
// lanes coalescing per line -> 16 line-lookups/instr instead of 64.
// Each lane owns (point, 8-channel chunk): accumulates all 8 corners locally,
// no cross-lane reduction. Stores: 16 consecutive n per 64B segment.
__global__ __launch_bounds__(256) void k_devox(const _Float16* __restrict__ gA,
                                               const f32x4* __restrict__ meta,
                                               float* __restrict__ out) {
    int w = blockIdx.x * 4 + (threadIdx.x >> 6);   // global wave id
    int lane = threadIdx.x & 63;
    int psub = lane & 15;
    int chunk = lane >> 4;
    int ct = w & 1;
    int group = w >> 1;                            // 0 .. B*N/16 - 1
    int b = group >> 12;                           // 4096 groups per batch
    int n0 = (group & 4095) << 4;
    int n = n0 + psub;

    f32x4 m = meta[(size_t)b * NPTS + n];
    float fx = m[0], fy = m[1], fz = m[2];
    int pk = __float_as_int(m[3]);
    int id0 = pk & 32767;
    int xo = ((pk >> 15) & 1) << 10;               // +1024 if x1 valid
    int yo = ((pk >> 16) & 1) << 5;                // +32
    int zo = (pk >> 17) & 1;                       // +1
    float gx = 1.f - fx, gy = 1.f - fy, gz = 1.f - fz;

    const _Float16* gb = gA + (size_t)(b * 2 + ct) * (RCELLS * 32) + chunk * 8;

    float acc[8];
#pragma unroll
    for (int j = 0; j < 8; ++j) acc[j] = 0.f;

#pragma unroll
    for (int c = 0; c < 8; ++c) {
        int id = id0 + ((c & 4) ? xo : 0) + ((c & 2) ? yo : 0) + ((c & 1) ? zo : 0);
        float wgt = ((c & 4) ? fx : gx) * ((c & 2) ? fy : gy) * ((c & 1) ? fz : gz);
        f16x8 v = *(const f16x8*)(gb + (size_t)id * 32);
#pragma unroll
        for (int j = 0; j < 8; ++j)
            acc[j] += wgt * (float)v[j];
    }

    float* ob = out + (size_t)b * CH * NPTS + (size_t)(ct * 32 + chunk * 8) * NPTS + n;
#pragma unroll
    for (int j = 0; j < 8; ++j)
        __builtin_nontemporal_store(acc[j], ob + (size_t)j * NPTS);
}

extern "C" void kernel_launch(void* const* d_in, const int* in_sizes, int n_in,
                              void* d_out, int out_size, void* d_ws, size_t ws_size,
                              hipStream_t stream) {
    const float* features = (const float*)d_in[0];
    const float* coords   = (const float*)d_in[1];
    const float* w1  = (const float*)d_in[2];
    const float* b1  = (const float*)d_in[3];
    const float* g1  = (const float*)d_in[4];
    const float* be1 = (const float*)d_in[5];
    const float* m1  = (const float*)d_in[6];
    const float* v1  = (const float*)d_in[7];
    const float* w2  = (const float*)d_in[8];
    const float* b2  = (const float*)d_in[9];
    const float* g2  = (const float*)d_in[10];
    const float* be2 = (const float*)d_in[11];
    const float* m2  = (const float*)d_in[12];
    const float* v2  = (const float*)d_in[13];

    float* ws = (float*)d_ws;
    float*        sums      = ws + OFF_SUMS;
    unsigned int* scaleBits = (unsigned int*)(ws + OFF_SCALE);
    int*          cnt       = (int*)(ws + OFF_CNT);
    int*          idxb      = (int*)(ws + OFF_IDX);
    int*          cellStart = (int*)(ws + OFF_CSTART);
    int*          order     = (int*)(ws + OFF_ORDER);
    float*        bnA1      = ws + OFF_BN;
    float*        bnB1      = ws + OFF_BN + 64;
    float*        bnA2      = ws + OFF_BN + 128;
    float*        bnB2      = ws + OFF_BN + 192;
    _Float16*     wP1       = (_Float16*)(ws + OFF_WP1);
    _Float16*     wP2       = (_Float16*)(ws + OFF_WP2);
    _Float16*     featT     = (_Float16*)(ws + OFF_FT);
    f32x4*        meta      = (f32x4*)(ws + OFF_META);   // aliases featT (free after gather)
    _Float16*     gA        = (_Float16*)(ws + OFF_GA);
    _Float16*     gB        = (_Float16*)(ws + OFF_GB);

    // zero: sums + scaleBits + cnt
    (void)hipMemsetAsync(ws, 0, (size_t)(OFF_IDX) * sizeof(float), stream);

    k_stats_sum<<<64, 256, 0, stream>>>(coords, sums);
    k_stats_max<<<64, 256, 0, stream>>>(coords, sums, scaleBits);
    k_vox_assign<<<(BATCH * NPTS) / 256, 256, 0, stream>>>(coords, sums, scaleBits,
                                                           idxb, cnt);
    k_scan<<<BATCH, 256, 0, stream>>>(cnt, cellStart);
    k_rank<<<(BATCH * NPTS) / 256, 256, 0, stream>>>(idxb, cellStart, order);
    k_transpose<<<(BATCH * NPTS) / 256, 256, 0, stream>>>(features, featT);
    k_gather<<<(BATCH * RCELLS * 2 * GSPLIT) / 256, 256, 0, stream>>>(
        featT, order, cellStart, cnt, gA);
    k_prep<<<432, 256, 0, stream>>>(w1, b1, g1, be1, m1, v1, wP1, bnA1, bnB1);
    k_prep<<<432, 256, 0, stream>>>(w2, b2, g2, be2, m2, v2, wP2, bnA2, bnB2);
    k_conv<<<BATCH * RES * 4, 256, 0, stream>>>(gA, gB, wP1, bnA1, bnB1);
    // featT is dead now -> overwrite with devox meta (overlaps conv2 in issue order)
    k_dprep<<<(BATCH * NPTS) / 256, 256, 0, stream>>>(coords, sums, scaleBits, meta);
    k_conv<<<BATCH * RES * 4, 256, 0, stream>>>(gB, gA, wP2, bnA2, bnB2);
    k_devox<<<(2 * BATCH * NPTS / 16) / 4, 256, 0, stream>>>(gA, meta, (float*)d_out);

    // append passthrough coords
    (void)hipMemcpyAsync((float*)d_out + (size_t)BATCH * CH * NPTS, coords,
                         (size_t)BATCH * 3 * NPTS * sizeof(float),
                         hipMemcpyDeviceToDevice, stream);
}

// Round 8
// 672.888 us; speedup vs baseline: 2.3901x; 1.0294x over previous
//
#include <hip/hip_runtime.h>
#include <hip/hip_bf16.h>
#include <hip/hip_fp16.h>

// Problem constants
#define NPTS   65536
#define BATCH  8
#define CH     64
#define RES    32
#define RCELLS 32768          // 32^3
#define NEG_SLOPE 0.1f
#define BN_EPS 1e-4f
#define GSPLIT 4              // point-parallel lanes per (cell, ct)

typedef float    f32x4 __attribute__((ext_vector_type(4)));
typedef _Float16 f16x8 __attribute__((ext_vector_type(8)));
typedef _Float16 f16x4 __attribute__((ext_vector_type(4)));

// Workspace layout (float offsets)
#define OFF_SUMS   0                                 // 24 floats
#define OFF_SCALE  24                                // 8 uints
#define OFF_CNT    32                                // B*32768 ints (zeroed)
#define OFF_IDX    (OFF_CNT + BATCH*RCELLS)          // B*N ints
#define OFF_CSTART (OFF_IDX + BATCH*NPTS)            // B*32768 ints
#define OFF_ORDER  (OFF_CSTART + BATCH*RCELLS)       // B*N ints
#define OFF_BN     (OFF_ORDER + BATCH*NPTS)          // 4*64 floats
#define OFF_WP1    (OFF_BN + 256)                    // 110592 f16 = 55296 fl
#define OFF_WP2    (OFF_WP1 + 55296)
#define OFF_FT     (OFF_WP2 + 55296)                 // B*N*64 f16 = 16777216 fl
#define OFF_GA     (OFF_FT + 16777216)               // 16777216 f16 = 8388608 fl
#define OFF_GB     (OFF_GA + 8388608)
// devox meta (float4 per point, 8 MB) reuses the featT area (free after gather)
#define OFF_META   OFF_FT

__device__ inline float waveReduceSum(float v) {
#pragma unroll
    for (int off = 32; off > 0; off >>= 1) v += __shfl_down(v, off, 64);
    return v;
}
__device__ inline float waveReduceMax(float v) {
#pragma unroll
    for (int off = 32; off > 0; off >>= 1) v = fmaxf(v, __shfl_down(v, off, 64));
    return v;
}

// ---------------- per-batch coordinate sums ----------------
__global__ __launch_bounds__(256) void k_stats_sum(const float* __restrict__ coords,
                                                   float* __restrict__ sums) {
    __shared__ float sm[3][4];
    int b = blockIdx.x >> 3, chunk = blockIdx.x & 7;
    const float* cb = coords + (size_t)b * 3 * NPTS;
    float s0 = 0.f, s1 = 0.f, s2 = 0.f;
    for (int i = threadIdx.x; i < 8192; i += 256) {
        int n = chunk * 8192 + i;
        s0 += cb[n];
        s1 += cb[n + NPTS];
        s2 += cb[n + 2 * NPTS];
    }
    s0 = waveReduceSum(s0); s1 = waveReduceSum(s1); s2 = waveReduceSum(s2);
    int lane = threadIdx.x & 63, wid = threadIdx.x >> 6;
    if (lane == 0) { sm[0][wid] = s0; sm[1][wid] = s1; sm[2][wid] = s2; }
    __syncthreads();
    if (threadIdx.x == 0) {
        atomicAdd(&sums[b * 3 + 0], sm[0][0] + sm[0][1] + sm[0][2] + sm[0][3]);
        atomicAdd(&sums[b * 3 + 1], sm[1][0] + sm[1][1] + sm[1][2] + sm[1][3]);
        atomicAdd(&sums[b * 3 + 2], sm[2][0] + sm[2][1] + sm[2][2] + sm[2][3]);
    }
}

// ---------------- per-batch max ||coord - mean|| ----------------
__global__ __launch_bounds__(256) void k_stats_max(const float* __restrict__ coords,
                                                   const float* __restrict__ sums,
                                                   unsigned int* __restrict__ scaleBits) {
    __shared__ float sm[4];
    int b = blockIdx.x >> 3, chunk = blockIdx.x & 7;
    const float* cb = coords + (size_t)b * 3 * NPTS;
    float mx = sums[b * 3 + 0] * (1.f / NPTS);
    float my = sums[b * 3 + 1] * (1.f / NPTS);
    float mz = sums[b * 3 + 2] * (1.f / NPTS);
    float m = 0.f;
    for (int i = threadIdx.x; i < 8192; i += 256) {
        int n = chunk * 8192 + i;
        float dx = cb[n] - mx, dy = cb[n + NPTS] - my, dz = cb[n + 2 * NPTS] - mz;
        m = fmaxf(m, sqrtf(dx * dx + dy * dy + dz * dz));
    }
    m = waveReduceMax(m);
    int lane = threadIdx.x & 63, wid = threadIdx.x >> 6;
    if (lane == 0) sm[wid] = m;
    __syncthreads();
    if (threadIdx.x == 0) {
        float r = fmaxf(fmaxf(sm[0], sm[1]), fmaxf(sm[2], sm[3]));
        atomicMax(&scaleBits[b], __float_as_uint(r));
    }
}

// ---------------- voxel index + int counts ----------------
__global__ __launch_bounds__(256) void k_vox_assign(const float* __restrict__ coords,
                                                    const float* __restrict__ sums,
                                                    const unsigned int* __restrict__ scaleBits,
                                                    int* __restrict__ idxb,
                                                    int* __restrict__ cnt) {
    int g = blockIdx.x * 256 + threadIdx.x;       // 0 .. B*N-1
    int b = g >> 16, n = g & (NPTS - 1);
    const float* cb = coords + (size_t)b * 3 * NPTS;
    float scale2 = __uint_as_float(scaleBits[b]) * 2.f;
    int v[3];
#pragma unroll
    for (int d = 0; d < 3; ++d) {
        float mean = sums[b * 3 + d] * (1.f / NPTS);
        float x = (cb[d * NPTS + n] - mean) / scale2 + 0.5f;
        x *= (float)RES;
        x = fminf(fmaxf(x, 0.f), (float)(RES - 1));
        v[d] = (int)rintf(x);
    }
    int id = (v[0] * RES + v[1]) * RES + v[2];
    idxb[b * NPTS + n] = id;
    atomicAdd(&cnt[b * RCELLS + id], 1);
}

// ---------------- per-batch exclusive prefix scan of cell counts ------------
__global__ __launch_bounds__(256) void k_scan(const int* __restrict__ cnt,
                                              int* __restrict__ cellStart) {
    __shared__ int bufA[256], bufB[256];
    int b = blockIdx.x, tid = threadIdx.x;
    const int* cb = cnt + b * RCELLS;
    int sum = 0;
    for (int i = 0; i < 128; ++i) sum += cb[tid * 128 + i];
    bufA[tid] = sum;
    __syncthreads();
    int* src = bufA; int* dst = bufB;
    for (int off = 1; off < 256; off <<= 1) {
        int v = src[tid];
        if (tid >= off) v += src[tid - off];
        dst[tid] = v;
        __syncthreads();
        int* t = src; src = dst; dst = t;
    }
    int run = (tid > 0) ? src[tid - 1] : 0;        // exclusive
    int* cs = cellStart + b * RCELLS;
    for (int i = 0; i < 128; ++i) {
        int c = cb[tid * 128 + i];
        cs[tid * 128 + i] = run;
        run += c;
    }
}

// ---------------- rank points into cell-sorted order ----------------
// Mutates cellStart: afterwards cellStart[c] == end offset of cell c.
__global__ __launch_bounds__(256) void k_rank(const int* __restrict__ idxb,
                                              int* __restrict__ cellStart,
                                              int* __restrict__ order) {
    int g = blockIdx.x * 256 + threadIdx.x;
    int b = g >> 16, n = g & (NPTS - 1);
    int cell = idxb[b * NPTS + n];
    int pos = atomicAdd(&cellStart[b * RCELLS + cell], 1);
    order[b * NPTS + pos] = n;
}

// ---------------- features fp32 [b][c][n] -> f16 [b][n][64] ----------------
__global__ __launch_bounds__(256) void k_transpose(const float* __restrict__ f,
                                                   _Float16* __restrict__ featT) {
    int g = blockIdx.x * 256 + threadIdx.x;        // 0 .. B*N-1
    int b = g >> 16, n = g & (NPTS - 1);
    const float* fb = f + (size_t)b * CH * NPTS + n;
    _Float16* dst = featT + (size_t)g * 64;
#pragma unroll
    for (int k = 0; k < 8; ++k) {
        f16x8 hv;
#pragma unroll
        for (int j = 0; j < 8; ++j)
            hv[j] = (_Float16)fb[(size_t)(k * 8 + j) * NPTS];
        *(f16x8*)(dst + k * 8) = hv;
    }
}

// ---------------- gather-average into f16 channels-last grid ----------------
// gA layout: [b][ct(2)][cell][32] f16.
// GSPLIT=4 lanes cooperate per (cell, ct): each accumulates a contiguous
// quarter of the cell's points (8-pt MLP unrolled), combined via shfl_xor.
// Block swizzle: bi = chunk*8 + b, so the 8 batches' copies of a hot (x,y)
// column are consecutive blocks -> spread across CUs instead of aliasing.
__global__ __launch_bounds__(256) void k_gather(const _Float16* __restrict__ featT,
                                                const int* __restrict__ order,
                                                const int* __restrict__ cellStart,
                                                const int* __restrict__ cnt,
                                                _Float16* __restrict__ gA) {
    int bi = blockIdx.x;                  // 0 .. B*RCELLS*2*GSPLIT/256 - 1
    int b  = bi & 7;
    int chunk = bi >> 3;                  // (x,y) column id, 0..1023
    int r  = chunk * 256 + threadIdx.x;   // 0 .. RCELLS*2*GSPLIT-1
    int sub  = r & (GSPLIT - 1);
    int ct   = (r >> 2) & 1;
    int cell = r >> 3;

    int e0 = cellStart[b * RCELLS + cell];         // post-rank: end offset
    int c  = cnt[b * RCELLS + cell];
    int s0 = e0 - c;
    int len = (c + GSPLIT - 1) >> 2;
    int s = s0 + sub * len;
    int e = min(s + len, e0);

    float acc[32];
#pragma unroll
    for (int j = 0; j < 32; ++j) acc[j] = 0.f;
    const int* ob = order + b * NPTS;
    const _Float16* fb = featT + (((size_t)b << 16)) * 64 + ct * 32;

    int p = s;
    for (; p + 8 <= e; p += 8) {
        int n[8];
#pragma unroll
        for (int u = 0; u < 8; ++u) n[u] = ob[p + u];   // 8 independent loads
        f16x8 v[8][4];
#pragma unroll
        for (int u = 0; u < 8; ++u) {
            const _Float16* q = fb + (size_t)n[u] * 64;
#pragma unroll
            for (int k = 0; k < 4; ++k)
                v[u][k] = *(const f16x8*)(q + k * 8);   // 32 loads in flight
        }
#pragma unroll
        for (int u = 0; u < 8; ++u)
#pragma unroll
            for (int k = 0; k < 4; ++k)
#pragma unroll
                for (int j = 0; j < 8; ++j)
                    acc[k * 8 + j] += (float)v[u][k][j];
    }
    for (; p < e; ++p) {
        int n = ob[p];
        const _Float16* q = fb + (size_t)n * 64;
#pragma unroll
        for (int k = 0; k < 4; ++k) {
            f16x8 vv = *(const f16x8*)(q + k * 8);
#pragma unroll
            for (int j = 0; j < 8; ++j)
                acc[k * 8 + j] += (float)vv[j];
        }
    }

    // combine the 4 point-split partial sums (lanes 4t..4t+3)
#pragma unroll
    for (int j = 0; j < 32; ++j) {
        acc[j] += __shfl_xor(acc[j], 1, 64);
        acc[j] += __shfl_xor(acc[j], 2, 64);
    }

    if (sub == 0) {
        float inv = 1.f / (float)max(c, 1);
        _Float16* dst = gA + ((size_t)(b * 2 + ct) * RCELLS + cell) * 32;
#pragma unroll
        for (int k = 0; k < 4; ++k) {
            f16x8 hv;
#pragma unroll
            for (int j = 0; j < 8; ++j)
                hv[j] = (_Float16)(acc[k * 8 + j] * inv);
            *(f16x8*)(dst + k * 8) = hv;
        }
    }
}

// ---------------- weight repack (f16, MFMA A-layout) + BN constants ----------
__global__ __launch_bounds__(256) void k_prep(const float* __restrict__ w,
                                              const float* __restrict__ bias,
                                              const float* __restrict__ g,
                                              const float* __restrict__ be,
                                              const float* __restrict__ m,
                                              const float* __restrict__ v,
                                              _Float16* __restrict__ wP,
                                              float* __restrict__ bnA,
                                              float* __restrict__ bnB) {
    int s = blockIdx.x * 256 + threadIdx.x;       // 0 .. 110591
    int ci_in = s & 31;
    int t  = s >> 5;
    int co = t & 63;
    int tc = t >> 6;                               // tap*2 + ct
    int ct = tc & 1;
    int tap = tc >> 1;
    int ci = ct * 32 + ci_in;
    wP[s] = (_Float16)w[co * 1728 + ci * 27 + tap];
    if (s < 64) {
        float A = g[s] / sqrtf(v[s] + BN_EPS);
        bnA[s] = A;
        bnB[s] = (bias[s] - m[s]) * A + be[s];
    }
}

// ---------------- 3x3x3 conv via f16 MFMA (implicit shift-GEMM) -------------
// T14 async-stage split: staging descriptors computed once; ct=1 global loads
// issued into registers BEFORE the ct=0 MFMA phase (latency hides under MFMA),
// then ds_write + barrier + MFMA ct=1. Removes the second exposed stage phase.
__global__ __launch_bounds__(256, 2) void k_conv(const _Float16* __restrict__ gIn,
                                                 _Float16* __restrict__ gOut,
                                                 const _Float16* __restrict__ wP,
                                                 const float* __restrict__ bnA,
                                                 const float* __restrict__ bnB) {
    __shared__ _Float16 sIn[3 * 10 * 34 * 32];     // 65280 B, halo-padded
    int bi = blockIdx.x;
    int b  = bi >> 7;
    int rem = bi & 127;
    int z  = rem >> 2;
    int yg = rem & 3;
    int tid = threadIdx.x;
    int wid = tid >> 6;
    int lane = tid & 63;
    int l15 = lane & 15, quad = lane >> 4;

    // per-thread staging descriptors, shared by both ct phases
    int soff[16], goff[16];
#pragma unroll
    for (int it = 0; it < 16; ++it) {
        int s = tid + it * 256;                    // 16B chunk id
        soff[it] = -1; goff[it] = -1;
        if (s < 4080) {
            int cc  = s & 3;
            int pos = s >> 2;                      // 0..1019
            int xx  = pos % 34;
            int t2  = pos / 34;
            int yy  = t2 % 10;
            int zz  = t2 / 10;
            int x = xx - 1, y = yg * 8 + yy - 1, z0 = z + zz - 1;
            soff[it] = s * 8;
            if ((unsigned)x < 32u && (unsigned)y < 32u && (unsigned)z0 < 32u)
                goff[it] = ((z0 * 32 + y) * 32 + x) * 32 + cc * 8;
        }
    }

    const _Float16* gin0 = gIn + (size_t)(b * 2) * (RCELLS * 32);
    const _Float16* gin1 = gin0 + (size_t)RCELLS * 32;

    // stage ct=0 into LDS
#pragma unroll
    for (int it = 0; it < 16; ++it) {
        if (soff[it] >= 0) {
            f32x4 val = {0.f, 0.f, 0.f, 0.f};
            if (goff[it] >= 0) val = *(const f32x4*)(gin0 + goff[it]);
            *(f32x4*)(sIn + soff[it]) = val;
        }
    }

    f32x4 acc[4][4];
#pragma unroll
    for (int mt = 0; mt < 4; ++mt)
#pragma unroll
        for (int nt = 0; nt < 4; ++nt) acc[mt][nt] = (f32x4){0.f, 0.f, 0.f, 0.f};

    int bbase[4];
#pragma unroll
    for (int nt = 0; nt < 4; ++nt) {
        int yl = 2 * wid + (nt >> 1);
        int x  = ((nt & 1) << 4) + l15;
        bbase[nt] = ((10 + (yl + 1)) * 34 + (x + 1)) * 32 + quad * 8; // zz=1
    }

    __syncthreads();

    // issue ct=1 global loads NOW; ~500cy latency hides under the ct=0 MFMAs
    f32x4 pre[16];
#pragma unroll
    for (int it = 0; it < 16; ++it) {
        f32x4 val = {0.f, 0.f, 0.f, 0.f};
        if (goff[it] >= 0) val = *(const f32x4*)(gin1 + goff[it]);
        pre[it] = val;
    }

    const f16x8* wp8 = (const f16x8*)wP;

#pragma unroll
    for (int ct = 0; ct < 2; ++ct) {
        if (ct == 1) {
            __syncthreads();                       // all waves done reading ct0
#pragma unroll
            for (int it = 0; it < 16; ++it)
                if (soff[it] >= 0) *(f32x4*)(sIn + soff[it]) = pre[it];
            __syncthreads();
        }

#pragma unroll
        for (int dz = -1; dz <= 1; ++dz)
#pragma unroll
        for (int dy = -1; dy <= 1; ++dy)
#pragma unroll
        for (int dx = -1; dx <= 1; ++dx) {
            int tap = (dz + 1) * 9 + (dy + 1) * 3 + (dx + 1);
            f16x8 aF[4];
#pragma unroll
            for (int mt = 0; mt < 4; ++mt)
                aF[mt] = wp8[tap * 512 + ct * 256 + mt * 64 + l15 * 4 + quad];
            f16x8 bF[4];
            int off = ((dz + 1) * 340 + dy * 34 + dx) * 32 - 340 * 32;
#pragma unroll
            for (int nt = 0; nt < 4; ++nt)
                bF[nt] = *(const f16x8*)(sIn + bbase[nt] + off);
#pragma unroll
            for (int mt = 0; mt < 4; ++mt)
#pragma unroll
                for (int nt = 0; nt < 4; ++nt)
                    acc[mt][nt] = __builtin_amdgcn_mfma_f32_16x16x32_f16(
                        aF[mt], bF[nt], acc[mt][nt], 0, 0, 0);
        }
    }

#pragma unroll
    for (int nt = 0; nt < 4; ++nt) {
        int y = yg * 8 + 2 * wid + (nt >> 1);
        int x = ((nt & 1) << 4) + l15;
        int cell = z * 1024 + y * 32 + x;
#pragma unroll
        for (int mt = 0; mt < 4; ++mt) {
            int cob = mt * 16 + quad * 4;           // 4 consecutive co
            f32x4 An = *(const f32x4*)(bnA + cob);
            f32x4 Bn = *(const f32x4*)(bnB + cob);
            f16x4 hv;
#pragma unroll
            for (int r = 0; r < 4; ++r) {
                float t = acc[mt][nt][r] * An[r] + Bn[r];
                t = (t >= 0.f) ? t : NEG_SLOPE * t;
                hv[r] = (_Float16)t;
            }
            _Float16* op = gOut + ((size_t)(b * 2 + (cob >> 5)) * RCELLS + cell) * 32 + (cob & 31);
            *(f16x4*)op = hv;
        }
    }
}

// ---------------- devox meta: per-point trilinear geometry -------------------
// meta[b*N+n] = {fx, fy, fz, bits(id0 | dx<<15 | dy<<16 | dz<<17)}
__global__ __launch_bounds__(256) void k_dprep(const float* __restrict__ coords,
                                               const float* __restrict__ sums,
                                               const unsigned int* __restrict__ scaleBits,
                                               f32x4* __restrict__ meta) {
    int g = blockIdx.x * 256 + threadIdx.x;        // 0 .. B*N-1
    int b = g >> 16, n = g & (NPTS - 1);
    const float* cb = coords + (size_t)b * 3 * NPTS;
    float scale2 = __uint_as_float(scaleBits[b]) * 2.f;
    float nc[3];
#pragma unroll
    for (int d = 0; d < 3; ++d) {
        float mean = sums[b * 3 + d] * (1.f / NPTS);
        float x = (cb[d * NPTS + n] - mean) / scale2 + 0.5f;
        x *= (float)RES;
        nc[d] = fminf(fmaxf(x, 0.f), (float)(RES - 1));
    }
    float lx = floorf(nc[0]), ly = floorf(nc[1]), lz = floorf(nc[2]);
    int x0 = (int)lx, y0 = (int)ly, z0 = (int)lz;
    int dx = (x0 + 1 <= RES - 1) ? 1 : 0;
    int dy = (y0 + 1 <= RES - 1) ? 1 : 0;
    int dz = (z0 + 1 <= RES - 1) ? 1 : 0;
    int id0 = (x0 * RES + y0) * RES + z0;
    int pk = id0 | (dx << 15) | (dy << 16) | (dz << 17);
    f32x4 m;
    m[0] = nc[0] - lx; m[1] = nc[1] - ly; m[2] = nc[2] - lz;
    m[3] = __int_as_float(pk);
    meta[(size_t)b * NPTS + n] = m;
}

// ---------------- trilinear devoxelize (wave-cooperative) -------------------
// Wave = 16 points x 4 chunks (lane = chunk*16 + psub); corner is the loop
// variable. Each load instruction covers 16 corner-rows (64B each) with 4
// lanes coalescing per line -> 16 line-lookups/instr instead of 64.
// Each lane owns (point, 8-channel chunk): accumulates all 8 corners locally,
// no cross-lane reduction. Stores: 16 consecutive n per 64B segment.
__global__ __launch_bounds__(256) void k_devox(const _Float16* __restrict__ gA,
                                               const f32x4* __restrict__ meta,
                                               float* __restrict__ out) {
    int w = blockIdx.x * 4 + (threadIdx.x >> 6);   // global wave id
    int lane = threadIdx.x & 63;
    int psub = lane & 15;
    int chunk = lane >> 4;
    int ct = w & 1;
    int group = w >> 1;                            // 0 .. B*N/16 - 1
    int b = group >> 12;                           // 4096 groups per batch
    int n0 = (group & 4095) << 4;
    int n = n0 + psub;

    f32x4 m = meta[(size_t)b * NPTS + n];
    float fx = m[0], fy = m[1], fz = m[2];
    int pk = __float_as_int(m[3]);
    int id0 = pk & 32767;
    int xo = ((pk >> 15) & 1) << 10;               // +1024 if x1 valid
    int yo = ((pk >> 16) & 1) << 5;                // +32
    int zo = (pk >> 17) & 1;                       // +1
    float gx = 1.f - fx, gy = 1.f - fy, gz = 1.f - fz;

    const _Float16* gb = gA + (size_t)(b * 2 + ct) * (RCELLS * 32) + chunk * 8;

    float acc[8];
#pragma unroll
    for (int j = 0; j < 8; ++j) acc[j] = 0.f;

#pragma unroll
    for (int c = 0; c < 8; ++c) {
        int id = id0 + ((c & 4) ? xo : 0) + ((c & 2) ? yo : 0) + ((c & 1) ? zo : 0);
        float wgt = ((c & 4) ? fx : gx) * ((c & 2) ? fy : gy) * ((c & 1) ? fz : gz);
        f16x8 v = *(const f16x8*)(gb + (size_t)id * 32);
#pragma unroll
        for (int j = 0; j < 8; ++j)
            acc[j] += wgt * (float)v[j];
    }

    float* ob = out + (size_t)b * CH * NPTS + (size_t)(ct * 32 + chunk * 8) * NPTS + n;
#pragma unroll
    for (int j = 0; j < 8; ++j)
        __builtin_nontemporal_store(acc[j], ob + (size_t)j * NPTS);
}

extern "C" void kernel_launch(void* const* d_in, const int* in_sizes, int n_in,
                              void* d_out, int out_size, void* d_ws, size_t ws_size,
                              hipStream_t stream) {
    const float* features = (const float*)d_in[0];
    const float* coords   = (const float*)d_in[1];
    const float* w1  = (const float*)d_in[2];
    const float* b1  = (const float*)d_in[3];
    const float* g1  = (const float*)d_in[4];
    const float* be1 = (const float*)d_in[5];
    const float* m1  = (const float*)d_in[6];
    const float* v1  = (const float*)d_in[7];
    const float* w2  = (const float*)d_in[8];
    const float* b2  = (const float*)d_in[9];
    const float* g2  = (const float*)d_in[10];
    const float* be2 = (const float*)d_in[11];
    const float* m2  = (const float*)d_in[12];
    const float* v2  = (const float*)d_in[13];

    float* ws = (float*)d_ws;
    float*        sums      = ws + OFF_SUMS;
    unsigned int* scaleBits = (unsigned int*)(ws + OFF_SCALE);
    int*          cnt       = (int*)(ws + OFF_CNT);
    int*          idxb      = (int*)(ws + OFF_IDX);
    int*          cellStart = (int*)(ws + OFF_CSTART);
    int*          order     = (int*)(ws + OFF_ORDER);
    float*        bnA1      = ws + OFF_BN;
    float*        bnB1      = ws + OFF_BN + 64;
    float*        bnA2      = ws + OFF_BN + 128;
    float*        bnB2      = ws + OFF_BN + 192;
    _Float16*     wP1       = (_Float16*)(ws + OFF_WP1);
    _Float16*     wP2       = (_Float16*)(ws + OFF_WP2);
    _Float16*     featT     = (_Float16*)(ws + OFF_FT);
    f32x4*        meta      = (f32x4*)(ws + OFF_META);   // aliases featT (free after gather)
    _Float16*     gA        = (_Float16*)(ws + OFF_GA);
    _Float16*     gB        = (_Float16*)(ws + OFF_GB);

    // zero: sums + scaleBits + cnt
    (void)hipMemsetAsync(ws, 0, (size_t)(OFF_IDX) * sizeof(float), stream);

    k_stats_sum<<<64, 256, 0, stream>>>(coords, sums);
    k_stats_max<<<64, 256, 0, stream>>>(coords, sums, scaleBits);
    k_vox_assign<<<(BATCH * NPTS) / 256, 256, 0, stream>>>(coords, sums, scaleBits,
                                                           idxb, cnt);
    k_scan<<<BATCH, 256, 0, stream>>>(cnt, cellStart);
    k_rank<<<(BATCH * NPTS) / 256, 256, 0, stream>>>(idxb, cellStart, order);
    k_transpose<<<(BATCH * NPTS) / 256, 256, 0, stream>>>(features, featT);
    k_gather<<<(BATCH * RCELLS * 2 * GSPLIT) / 256, 256, 0, stream>>>(
        featT, order, cellStart, cnt, gA);
    k_prep<<<432, 256, 0, stream>>>(w1, b1, g1, be1, m1, v1, wP1, bnA1, bnB1);
    k_prep<<<432, 256, 0, stream>>>(w2, b2, g2, be2, m2, v2, wP2, bnA2, bnB2);
    k_conv<<<BATCH * RES * 4, 256, 0, stream>>>(gA, gB, wP1, bnA1, bnB1);
    // featT is dead now -> overwrite with devox meta (overlaps conv2 in issue order)
    k_dprep<<<(BATCH * NPTS) / 256, 256, 0, stream>>>(coords, sums, scaleBits, meta);
    k_conv<<<BATCH * RES * 4, 256, 0, stream>>>(gB, gA, wP2, bnA2, bnB2);
    k_devox<<<(2 * BATCH * NPTS / 16) / 4, 256, 0, stream>>>(gA, meta, (float*)d_out);

    // append passthrough coords
    (void)hipMemcpyAsync((float*)d_out + (size_t)BATCH * CH * NPTS, coords,
                         (size_t)BATCH * 3 * NPTS * sizeof(float),
                         hipMemcpyDeviceToDevice, stream);
}